// Round 1
// baseline (800.829 us; speedup 1.0000x reference)
//
#include <hip/hip_runtime.h>
#include <math.h>

#define NN   65536
#define BB   256
#define NPGC 256
#define EE   1048576
#define DD   128
#define KK   128
#define NT2  32768
#define OUTD 12
#define BN_EPS 1e-5f

// ---------------- Atom encoder ----------------
__global__ void k_atom(const int* __restrict__ x, const float* __restrict__ emb,
                       float* __restrict__ h) {
    int n = blockIdx.x, d = threadIdx.x;
    __shared__ int xr[9];
    if (d < 9) xr[d] = x[n * 9 + d];
    __syncthreads();
    float acc = 0.f;
#pragma unroll
    for (int f = 0; f < 9; ++f) acc += emb[(f * 128 + xr[f]) * DD + d];
    h[n * DD + d] = acc;
}

// ---------------- CSR build ----------------
__global__ void k_count(const int* __restrict__ dst, int* __restrict__ counts, int n) {
    int i = blockIdx.x * blockDim.x + threadIdx.x;
    if (i < n) atomicAdd(&counts[dst[i]], 1);
}

__global__ void k_scanA(const int* __restrict__ in, int* __restrict__ out, int* __restrict__ bs) {
    __shared__ int s[256];
    int t = threadIdx.x, i = blockIdx.x * 256 + t;
    int v = in[i];
    s[t] = v; __syncthreads();
    for (int d = 1; d < 256; d <<= 1) {
        int u = (t >= d) ? s[t - d] : 0;
        __syncthreads();
        s[t] += u;
        __syncthreads();
    }
    out[i] = s[t] - v;
    if (t == 255) bs[blockIdx.x] = s[255];
}

__global__ void k_scanB(int* bs, int nb) {
    __shared__ int s[256];
    int t = threadIdx.x;
    int v = (t < nb) ? bs[t] : 0;
    s[t] = v; __syncthreads();
    for (int d = 1; d < 256; d <<= 1) {
        int u = (t >= d) ? s[t - d] : 0;
        __syncthreads();
        s[t] += u;
        __syncthreads();
    }
    if (t < nb) bs[t] = s[t] - v;
}

__global__ void k_scanC(int* out, const int* __restrict__ bs) {
    int i = blockIdx.x * 256 + threadIdx.x;
    out[i] += bs[blockIdx.x];
}

__global__ void k_place(const int* __restrict__ src, const int* __restrict__ dst,
                        const int* __restrict__ off, int* __restrict__ cur,
                        int* __restrict__ csr, int n) {
    int i = blockIdx.x * blockDim.x + threadIdx.x;
    if (i < n) {
        int d = dst[i];
        int slot = off[d] + atomicAdd(&cur[d], 1);
        csr[slot] = src[i];
    }
}

__global__ void k_count2(const int* __restrict__ src, const int* __restrict__ dst,
                         const int* __restrict__ inv, int* __restrict__ counts, int n) {
    int i = blockIdx.x * blockDim.x + threadIdx.x;
    if (i < n) {
        int s = inv[src[i]], d = inv[dst[i]];
        if (s < NT2 && d < NT2) atomicAdd(&counts[d], 1);
    }
}

__global__ void k_place2(const int* __restrict__ src, const int* __restrict__ dst,
                         const int* __restrict__ inv, const int* __restrict__ off,
                         int* __restrict__ cur, int* __restrict__ csr, int n) {
    int i = blockIdx.x * blockDim.x + threadIdx.x;
    if (i < n) {
        int s = inv[src[i]], d = inv[dst[i]];
        if (s < NT2 && d < NT2) {
            int slot = off[d] + atomicAdd(&cur[d], 1);
            csr[slot] = s;
        }
    }
}

// ---------------- GIN aggregate: out[n] = (1+eps)*h[n] + sum_{j in CSR(n)} h[src_j] ----------------
__global__ void k_agg(const float* __restrict__ h, const int* __restrict__ off,
                      const int* __restrict__ deg, const int* __restrict__ csr,
                      const float* __restrict__ epsArr, int layer, float* __restrict__ out) {
    int n = blockIdx.x, d = threadIdx.x;
    int start = off[n], dg = deg[n];
    float acc = (1.f + epsArr[layer]) * h[n * DD + d];
    __shared__ int nb[128];
    for (int base = 0; base < dg; base += 128) {
        int m = dg - base; if (m > 128) m = 128;
        if (d < m) nb[d] = csr[start + base + d];
        __syncthreads();
        for (int j = 0; j < m; ++j) acc += h[nb[j] * DD + d];
        __syncthreads();
    }
    out[n * DD + d] = acc;
}

// ---------------- In-place matmul: z = z @ W[layer] + b[layer] ----------------
#define MMR 32
#define APAD 36
__global__ __launch_bounds__(256) void k_mm(float* __restrict__ z, const float* __restrict__ Wg,
                                            const float* __restrict__ bg, int layer) {
    __shared__ float Wl[64 * DD];    // 32KB: half of W
    __shared__ float Al[DD * APAD];  // 18KB: transposed A tile (pad 36 vs 32)
    const float* W = Wg + layer * DD * DD;
    int t = threadIdx.x;
    int row0 = blockIdx.x * MMR;

    // stage A transposed: Al[k*APAD + r] = z[row0+r][k]; coalesced global reads
    for (int i = t; i < MMR * DD; i += 256) {
        int r = i >> 7, k = i & 127;
        Al[k * APAD + r] = z[(row0 + r) * DD + k];
    }

    int tr = t >> 5, tc = t & 31;
    float acc[4][4] = {};

    for (int kh = 0; kh < 2; ++kh) {
        __syncthreads();
        const float4* Wsrc = (const float4*)(W + kh * 64 * DD);
        float4* Wd = (float4*)Wl;
        for (int i = t; i < 64 * DD / 4; i += 256) Wd[i] = Wsrc[i];
        __syncthreads();
#pragma unroll 4
        for (int kk = 0; kk < 64; ++kk) {
            int k = kh * 64 + kk;
            float4 a = *(const float4*)&Al[k * APAD + (tr << 2)];
            float4 w = *(const float4*)&Wl[kk * DD + (tc << 2)];
            acc[0][0] += a.x * w.x; acc[0][1] += a.x * w.y; acc[0][2] += a.x * w.z; acc[0][3] += a.x * w.w;
            acc[1][0] += a.y * w.x; acc[1][1] += a.y * w.y; acc[1][2] += a.y * w.z; acc[1][3] += a.y * w.w;
            acc[2][0] += a.z * w.x; acc[2][1] += a.z * w.y; acc[2][2] += a.z * w.z; acc[2][3] += a.z * w.w;
            acc[3][0] += a.w * w.x; acc[3][1] += a.w * w.y; acc[3][2] += a.w * w.z; acc[3][3] += a.w * w.w;
        }
    }

    const float* bias = bg + layer * DD;
    float4 bv = *(const float4*)&bias[tc << 2];
#pragma unroll
    for (int i = 0; i < 4; ++i) {
        int r = row0 + (tr << 2) + i;
        float4 o;
        o.x = acc[i][0] + bv.x; o.y = acc[i][1] + bv.y;
        o.z = acc[i][2] + bv.z; o.w = acc[i][3] + bv.w;
        *(float4*)&z[r * DD + (tc << 2)] = o;
    }
}

// ---------------- BatchNorm stats (sum, sumsq per channel) ----------------
__global__ void k_bnstats(const float* __restrict__ z, float* __restrict__ stats, int nrows) {
    int d = threadIdx.x;  // 128
    int rows_per = nrows / gridDim.x;
    int r0 = blockIdx.x * rows_per;
    float s = 0.f, q = 0.f;
    for (int r = r0; r < r0 + rows_per; ++r) {
        float v = z[r * DD + d];
        s += v; q += v * v;
    }
    atomicAdd(&stats[d], s);
    atomicAdd(&stats[DD + d], q);
}

// ---------------- BN apply + ReLU ----------------
__global__ void k_bnapply(const float* __restrict__ z, const float* __restrict__ stats,
                          const float* __restrict__ gam, const float* __restrict__ bet,
                          int layer, float* __restrict__ out, int nrows) {
    __shared__ float scale[DD], shift[DD];
    int t = threadIdx.x;  // 256
    if (t < DD) {
        float invN = 1.f / (float)nrows;
        float mu = stats[t] * invN;
        float var = stats[DD + t] * invN - mu * mu;
        float istd = rsqrtf(var + BN_EPS);
        float g = gam[layer * DD + t], b = bet[layer * DD + t];
        scale[t] = g * istd;
        shift[t] = b - mu * g * istd;
    }
    __syncthreads();
    int total = nrows * DD;
    for (int i = blockIdx.x * blockDim.x + t; i < total; i += gridDim.x * blockDim.x) {
        int d = i & (DD - 1);
        float v = z[i] * scale[d] + shift[d];
        out[i] = v > 0.f ? v : 0.f;
    }
}

// ---------------- TopK scoring ----------------
__global__ void k_wnorm(const float* __restrict__ w, float* __restrict__ invn) {
    __shared__ float s[128];
    int t = threadIdx.x;
    float v = w[t];
    s[t] = v * v; __syncthreads();
    for (int d = 64; d > 0; d >>= 1) {
        if (t < d) s[t] += s[t + d];
        __syncthreads();
    }
    if (t == 0) *invn = rsqrtf(s[0]);
}

__global__ void k_score(const float* __restrict__ h, const float* __restrict__ w,
                        const float* __restrict__ invn, float* __restrict__ score) {
    int n = blockIdx.x, t = threadIdx.x;  // 128
    float p = h[n * DD + t] * w[t];
    for (int off = 32; off > 0; off >>= 1) p += __shfl_down(p, off);
    __shared__ float s2[2];
    if ((t & 63) == 0) s2[t >> 6] = p;
    __syncthreads();
    if (t == 0) score[n] = (s2[0] + s2[1]) * (*invn);
}

// ---------------- TopK selection (rank counting; set-equivalent to reference) ----------------
__global__ void k_topk(const float* __restrict__ score, int* __restrict__ inv,
                       int* __restrict__ perm) {
    int g = blockIdx.x, t = threadIdx.x;  // 256
    __shared__ float s[NPGC];
    __shared__ unsigned char fl[NPGC];
    int n = g * NPGC + t;
    float v = score[n];
    s[t] = v; __syncthreads();
    int rank = 0;
    for (int j = 0; j < NPGC; ++j) {
        float u = s[j];
        rank += (u > v) || (u == v && j < t);
    }
    int sel = rank < KK;
    fl[t] = (unsigned char)sel;
    __syncthreads();
    int idx = 0;
    for (int j = 0; j < t; ++j) idx += fl[j];
    if (sel) {
        int m = g * KK + idx;
        perm[m] = n;
        inv[n] = m;
    } else {
        inv[n] = NT2;
    }
}

// ---------------- Gate: h2[m] = h[perm[m]] * tanh(score[perm[m]]) ----------------
__global__ void k_gate(const float* __restrict__ h, const float* __restrict__ score,
                       const int* __restrict__ perm, float* __restrict__ out) {
    int m = blockIdx.x, d = threadIdx.x;
    int n = perm[m];
    out[m * DD + d] = h[n * DD + d] * tanhf(score[n]);
}

// ---------------- Mean-pool + output head + sigmoid ----------------
__global__ void k_final(const float* __restrict__ h, const float* __restrict__ oW,
                        const float* __restrict__ ob, float* __restrict__ out) {
    int g = blockIdx.x, t = threadIdx.x;  // 128
    float acc = 0.f;
    for (int m = 0; m < KK; ++m) acc += h[(g * KK + m) * DD + t];
    __shared__ float pooled[DD];
    pooled[t] = acc * (1.f / (float)KK);
    __syncthreads();
    if (t < OUTD) {
        float o = ob[t];
        for (int k = 0; k < DD; ++k) o += pooled[k] * oW[k * OUTD + t];
        out[g * OUTD + t] = 1.f / (1.f + expf(-o));
    }
}

extern "C" void kernel_launch(void* const* d_in, const int* in_sizes, int n_in,
                              void* d_out, int out_size, void* d_ws, size_t ws_size,
                              hipStream_t stream) {
    const int*   x        = (const int*)d_in[0];
    const int*   ei       = (const int*)d_in[1];  // src = ei[0:E], dst = ei[E:2E]
    const float* atom_emb = (const float*)d_in[4];
    const float* convW    = (const float*)d_in[6];
    const float* convb    = (const float*)d_in[7];
    const float* gam      = (const float*)d_in[8];
    const float* bet      = (const float*)d_in[9];
    const float* eps      = (const float*)d_in[10];
    const float* tw       = (const float*)d_in[11];
    const float* oW       = (const float*)d_in[12];
    const float* ob       = (const float*)d_in[13];
    float* out = (float*)d_out;

    char* p = (char*)d_ws;
    float* hA     = (float*)p; p += (size_t)NN * DD * 4;
    float* hB     = (float*)p; p += (size_t)NN * DD * 4;
    int* counts1  = (int*)p;   p += (size_t)NN * 4;
    int* off1     = (int*)p;   p += (size_t)NN * 4;
    int* cur1     = (int*)p;   p += (size_t)NN * 4;
    int* csr1     = (int*)p;   p += (size_t)EE * 4;
    int* counts2  = (int*)p;   p += (size_t)NT2 * 4;
    int* off2     = (int*)p;   p += (size_t)NT2 * 4;
    int* cur2     = (int*)p;   p += (size_t)NT2 * 4;
    int* csr2     = (int*)p;   p += (size_t)EE * 4;
    float* score  = (float*)p; p += (size_t)NN * 4;
    int* invm     = (int*)p;   p += (size_t)NN * 4;
    int* perm     = (int*)p;   p += (size_t)NT2 * 4;
    float* bnst   = (float*)p; p += (size_t)2 * DD * 4;
    int* bsums    = (int*)p;   p += (size_t)256 * 4;
    float* invn   = (float*)p; p += 16;
    if ((size_t)(p - (char*)d_ws) > ws_size) return;  // insufficient workspace

    const int* src = ei;
    const int* dst = ei + EE;

    // Atom encoder
    k_atom<<<NN, 128, 0, stream>>>(x, atom_emb, hA);

    // Phase-1 CSR
    hipMemsetAsync(counts1, 0, (size_t)NN * 4, stream);
    k_count<<<EE / 256, 256, 0, stream>>>(dst, counts1, EE);
    k_scanA<<<NN / 256, 256, 0, stream>>>(counts1, off1, bsums);
    k_scanB<<<1, 256, 0, stream>>>(bsums, NN / 256);
    k_scanC<<<NN / 256, 256, 0, stream>>>(off1, bsums);
    hipMemsetAsync(cur1, 0, (size_t)NN * 4, stream);
    k_place<<<EE / 256, 256, 0, stream>>>(src, dst, off1, cur1, csr1, EE);

    // Layers 0..2 on N nodes
    for (int layer = 0; layer < 3; ++layer) {
        k_agg<<<NN, 128, 0, stream>>>(hA, off1, cur1, csr1, eps, layer, hB);
        k_mm<<<NN / MMR, 256, 0, stream>>>(hB, convW, convb, layer);
        hipMemsetAsync(bnst, 0, 2 * DD * 4, stream);
        k_bnstats<<<512, 128, 0, stream>>>(hB, bnst, NN);
        k_bnapply<<<2048, 256, 0, stream>>>(hB, bnst, gam, bet, layer, hA, NN);
    }

    // TopK pooling
    k_wnorm<<<1, 128, 0, stream>>>(tw, invn);
    k_score<<<NN, 128, 0, stream>>>(hA, tw, invn, score);
    k_topk<<<BB, 256, 0, stream>>>(score, invm, perm);
    k_gate<<<NT2, 128, 0, stream>>>(hA, score, perm, hB);

    // Phase-2 CSR (valid remapped edges only)
    hipMemsetAsync(counts2, 0, (size_t)NT2 * 4, stream);
    k_count2<<<EE / 256, 256, 0, stream>>>(src, dst, invm, counts2, EE);
    k_scanA<<<NT2 / 256, 256, 0, stream>>>(counts2, off2, bsums);
    k_scanB<<<1, 256, 0, stream>>>(bsums, NT2 / 256);
    k_scanC<<<NT2 / 256, 256, 0, stream>>>(off2, bsums);
    hipMemsetAsync(cur2, 0, (size_t)NT2 * 4, stream);
    k_place2<<<EE / 256, 256, 0, stream>>>(src, dst, invm, off2, cur2, csr2, EE);

    // Layers 3..4 on N2 nodes
    for (int layer = 3; layer < 5; ++layer) {
        k_agg<<<NT2, 128, 0, stream>>>(hB, off2, cur2, csr2, eps, layer, hA);
        k_mm<<<NT2 / MMR, 256, 0, stream>>>(hA, convW, convb, layer);
        hipMemsetAsync(bnst, 0, 2 * DD * 4, stream);
        k_bnstats<<<256, 128, 0, stream>>>(hA, bnst, NT2);
        k_bnapply<<<2048, 256, 0, stream>>>(hA, bnst, gam, bet, layer, hB, NT2);
    }

    // Head
    k_final<<<BB, 128, 0, stream>>>(hB, oW, ob, out);
}

// Round 3
// 560.616 us; speedup vs baseline: 1.4285x; 1.4285x over previous
//
#include <hip/hip_runtime.h>
#include <math.h>

#define NN   65536
#define BB   256
#define NPGC 256
#define EE   1048576
#define DD   128
#define KK   128
#define NT2  32768
#define OUTD 12
#define BN_EPS 1e-5f

// ---------------- Atom encoder ----------------
__global__ void k_atom(const int* __restrict__ x, const float* __restrict__ emb,
                       float* __restrict__ h) {
    int n = blockIdx.x, d = threadIdx.x;
    __shared__ int xr[9];
    if (d < 9) xr[d] = x[n * 9 + d];
    __syncthreads();
    float acc = 0.f;
#pragma unroll
    for (int f = 0; f < 9; ++f) acc += emb[(f * 128 + xr[f]) * DD + d];
    h[n * DD + d] = acc;
}

// ---------------- CSR build ----------------
__global__ void k_count(const int* __restrict__ dst, int* __restrict__ counts, int n) {
    int i = blockIdx.x * blockDim.x + threadIdx.x;
    if (i < n) atomicAdd(&counts[dst[i]], 1);
}

__global__ void k_scanA(const int* __restrict__ in, int* __restrict__ out, int* __restrict__ bs) {
    __shared__ int s[256];
    int t = threadIdx.x, i = blockIdx.x * 256 + t;
    int v = in[i];
    s[t] = v; __syncthreads();
    for (int d = 1; d < 256; d <<= 1) {
        int u = (t >= d) ? s[t - d] : 0;
        __syncthreads();
        s[t] += u;
        __syncthreads();
    }
    out[i] = s[t] - v;
    if (t == 255) bs[blockIdx.x] = s[255];
}

__global__ void k_scanB(int* bs, int nb) {
    __shared__ int s[256];
    int t = threadIdx.x;
    int v = (t < nb) ? bs[t] : 0;
    s[t] = v; __syncthreads();
    for (int d = 1; d < 256; d <<= 1) {
        int u = (t >= d) ? s[t - d] : 0;
        __syncthreads();
        s[t] += u;
        __syncthreads();
    }
    if (t < nb) bs[t] = s[t] - v;
}

__global__ void k_scanC(int* out, const int* __restrict__ bs) {
    int i = blockIdx.x * 256 + threadIdx.x;
    out[i] += bs[blockIdx.x];
}

__global__ void k_place(const int* __restrict__ src, const int* __restrict__ dst,
                        const int* __restrict__ off, int* __restrict__ cur,
                        int* __restrict__ csr, int n) {
    int i = blockIdx.x * blockDim.x + threadIdx.x;
    if (i < n) {
        int d = dst[i];
        int slot = off[d] + atomicAdd(&cur[d], 1);
        csr[slot] = src[i];
    }
}

__global__ void k_count2(const int* __restrict__ src, const int* __restrict__ dst,
                         const int* __restrict__ inv, int* __restrict__ counts, int n) {
    int i = blockIdx.x * blockDim.x + threadIdx.x;
    if (i < n) {
        int s = inv[src[i]], d = inv[dst[i]];
        if (s < NT2 && d < NT2) atomicAdd(&counts[d], 1);
    }
}

__global__ void k_place2(const int* __restrict__ src, const int* __restrict__ dst,
                         const int* __restrict__ inv, const int* __restrict__ off,
                         int* __restrict__ cur, int* __restrict__ csr, int n) {
    int i = blockIdx.x * blockDim.x + threadIdx.x;
    if (i < n) {
        int s = inv[src[i]], d = inv[dst[i]];
        if (s < NT2 && d < NT2) {
            int slot = off[d] + atomicAdd(&cur[d], 1);
            csr[slot] = s;
        }
    }
}

// ---------------- Fused BN(prev)+ReLU + GIN aggregate, one graph per block ----------------
// LDS: whole graph's rows (BN'd) + whole graph's edge list. Gathers are LDS b64.
template<int NPG_T>
__global__ __launch_bounds__(1024) void k_agg_f(
    const float* __restrict__ zin, const float* __restrict__ stats,
    const float* __restrict__ gamL, const float* __restrict__ betL,
    float invRows, int doBN,
    const float* __restrict__ epsArr, int layer,
    const int* __restrict__ off, const int* __restrict__ deg,
    const int* __restrict__ csr, float* __restrict__ aout)
{
    __shared__ float A[NPG_T * DD];
    __shared__ int nbl[4096];
    __shared__ float sc[DD], sh[DD];
    const int g = blockIdx.x;
    const int t = threadIdx.x;
    const int nbase = g * NPG_T;

    if (doBN && t < DD) {
        float mu = stats[t] * invRows;
        float var = stats[DD + t] * invRows - mu * mu;
        float istd = rsqrtf(var + BN_EPS);
        float ga = gamL[t], be = betL[t];
        sc[t] = ga * istd;
        sh[t] = be - mu * ga * istd;
    }
    // stage this graph's edge list (csr slots for a graph are contiguous)
    const int e0 = off[nbase];
    const int eCnt = off[nbase + NPG_T - 1] + deg[nbase + NPG_T - 1] - e0;
    for (int i = t; i < eCnt; i += 1024) nbl[i] = csr[e0 + i] - nbase;
    __syncthreads();  // sc/sh ready

    // load rows + BN + ReLU into LDS
    const float4* zin4 = (const float4*)(zin + (size_t)nbase * DD);
    float4* A4 = (float4*)A;
    for (int i = t; i < NPG_T * DD / 4; i += 1024) {
        float4 v = zin4[i];
        if (doBN) {
            int c = (i << 2) & (DD - 1);
            v.x = fmaxf(v.x * sc[c] + sh[c], 0.f);
            v.y = fmaxf(v.y * sc[c + 1] + sh[c + 1], 0.f);
            v.z = fmaxf(v.z * sc[c + 2] + sh[c + 2], 0.f);
            v.w = fmaxf(v.w * sc[c + 3] + sh[c + 3], 0.f);
        }
        A4[i] = v;
    }
    __syncthreads();  // A + nbl ready

    const float opEps = 1.f + epsArr[layer];
    const int wave = t >> 6, lane = t & 63;
    const float2* A2 = (const float2*)A;
    constexpr int NPW = NPG_T / 16;  // nodes per wave (16 waves)
#pragma unroll
    for (int i = 0; i < NPW; ++i) {
        int node = wave * NPW + i;
        int gnode = nbase + node;
        int st = off[gnode] - e0;
        int dg = deg[gnode];
        float2 self = A2[node * 64 + lane];
        float ax = self.x * opEps, ay = self.y * opEps;
        int j = 0;
        for (; j + 3 < dg; j += 4) {  // 4-deep ILP on the LDS gather chain
            int n0 = nbl[st + j], n1 = nbl[st + j + 1], n2 = nbl[st + j + 2], n3 = nbl[st + j + 3];
            float2 v0 = A2[n0 * 64 + lane];
            float2 v1 = A2[n1 * 64 + lane];
            float2 v2 = A2[n2 * 64 + lane];
            float2 v3 = A2[n3 * 64 + lane];
            ax += v0.x + v1.x + v2.x + v3.x;
            ay += v0.y + v1.y + v2.y + v3.y;
        }
        for (; j < dg; ++j) {
            int nb = nbl[st + j];
            float2 v = A2[nb * 64 + lane];
            ax += v.x; ay += v.y;
        }
        float2 o; o.x = ax; o.y = ay;
        ((float2*)aout)[(size_t)gnode * 64 + lane] = o;
    }
}

// ---------------- In-place matmul + fused BN stats: z = z @ W[layer] + b ----------------
#define MMR 32
#define APAD 36
__global__ __launch_bounds__(256) void k_mm(float* __restrict__ z, const float* __restrict__ Wg,
                                            const float* __restrict__ bg, int layer,
                                            float* __restrict__ stats) {
    __shared__ float Wl[64 * DD];
    __shared__ float Al[DD * APAD];
    const float* W = Wg + layer * DD * DD;
    int t = threadIdx.x;
    int row0 = blockIdx.x * MMR;

    for (int i = t; i < MMR * DD; i += 256) {
        int r = i >> 7, k = i & 127;
        Al[k * APAD + r] = z[(row0 + r) * DD + k];
    }

    int tr = t >> 5, tc = t & 31;
    float acc[4][4] = {};

    for (int kh = 0; kh < 2; ++kh) {
        __syncthreads();
        const float4* Wsrc = (const float4*)(W + kh * 64 * DD);
        float4* Wd = (float4*)Wl;
        for (int i = t; i < 64 * DD / 4; i += 256) Wd[i] = Wsrc[i];
        __syncthreads();
#pragma unroll 4
        for (int kk = 0; kk < 64; ++kk) {
            int k = kh * 64 + kk;
            float4 a = *(const float4*)&Al[k * APAD + (tr << 2)];
            float4 w = *(const float4*)&Wl[kk * DD + (tc << 2)];
            acc[0][0] += a.x * w.x; acc[0][1] += a.x * w.y; acc[0][2] += a.x * w.z; acc[0][3] += a.x * w.w;
            acc[1][0] += a.y * w.x; acc[1][1] += a.y * w.y; acc[1][2] += a.y * w.z; acc[1][3] += a.y * w.w;
            acc[2][0] += a.z * w.x; acc[2][1] += a.z * w.y; acc[2][2] += a.z * w.z; acc[2][3] += a.z * w.w;
            acc[3][0] += a.w * w.x; acc[3][1] += a.w * w.y; acc[3][2] += a.w * w.z; acc[3][3] += a.w * w.w;
        }
    }

    const float* bias = bg + layer * DD;
    float4 bv = *(const float4*)&bias[tc << 2];
    float cs[4] = {0.f, 0.f, 0.f, 0.f}, cq[4] = {0.f, 0.f, 0.f, 0.f};
#pragma unroll
    for (int i = 0; i < 4; ++i) {
        int r = row0 + (tr << 2) + i;
        float4 o;
        o.x = acc[i][0] + bv.x; o.y = acc[i][1] + bv.y;
        o.z = acc[i][2] + bv.z; o.w = acc[i][3] + bv.w;
        *(float4*)&z[r * DD + (tc << 2)] = o;
        cs[0] += o.x; cq[0] += o.x * o.x;
        cs[1] += o.y; cq[1] += o.y * o.y;
        cs[2] += o.z; cq[2] += o.z * o.z;
        cs[3] += o.w; cq[3] += o.w * o.w;
    }
    // block-level BN-stat reduction (reuse Al), one atomic per channel per stat
    __syncthreads();
    float* Ps = Al;
    float* Qs = Al + 1024;
#pragma unroll
    for (int i = 0; i < 4; ++i) {
        Ps[(tr << 7) + (tc << 2) + i] = cs[i];
        Qs[(tr << 7) + (tc << 2) + i] = cq[i];
    }
    __syncthreads();
    if (t < DD) {
        float s = 0.f, q = 0.f;
#pragma unroll
        for (int r = 0; r < 8; ++r) { s += Ps[(r << 7) + t]; q += Qs[(r << 7) + t]; }
        atomicAdd(&stats[t], s);
        atomicAdd(&stats[DD + t], q);
    }
}

// ---------------- BN scale/shift materialization (tiny) ----------------
__global__ void k_mkbn(const float* __restrict__ stats, const float* __restrict__ gamL,
                       const float* __restrict__ betL, float invRows, float* __restrict__ scsh) {
    int t = threadIdx.x;  // 128
    float mu = stats[t] * invRows;
    float var = stats[DD + t] * invRows - mu * mu;
    float istd = rsqrtf(var + BN_EPS);
    float ga = gamL[t], be = betL[t];
    scsh[t] = ga * istd;
    scsh[DD + t] = be - mu * ga * istd;
}

// ---------------- TopK scoring (BN fused) ----------------
__global__ void k_wnorm(const float* __restrict__ w, float* __restrict__ invn) {
    __shared__ float s[128];
    int t = threadIdx.x;
    float v = w[t];
    s[t] = v * v; __syncthreads();
    for (int d = 64; d > 0; d >>= 1) {
        if (t < d) s[t] += s[t + d];
        __syncthreads();
    }
    if (t == 0) *invn = rsqrtf(s[0]);
}

__global__ void k_score(const float* __restrict__ z, const float* __restrict__ scsh,
                        const float* __restrict__ w, const float* __restrict__ invn,
                        float* __restrict__ score) {
    int n = blockIdx.x, t = threadIdx.x;  // 128
    float v = fmaxf(z[n * DD + t] * scsh[t] + scsh[DD + t], 0.f);
    float p = v * w[t];
    for (int off = 32; off > 0; off >>= 1) p += __shfl_down(p, off);
    __shared__ float s2[2];
    if ((t & 63) == 0) s2[t >> 6] = p;
    __syncthreads();
    if (t == 0) score[n] = (s2[0] + s2[1]) * (*invn);
}

// ---------------- TopK selection (rank counting; set-equivalent to reference) ----------------
__global__ void k_topk(const float* __restrict__ score, int* __restrict__ inv,
                       int* __restrict__ perm) {
    int g = blockIdx.x, t = threadIdx.x;  // 256
    __shared__ float s[NPGC];
    __shared__ unsigned char fl[NPGC];
    int n = g * NPGC + t;
    float v = score[n];
    s[t] = v; __syncthreads();
    int rank = 0;
    for (int j = 0; j < NPGC; ++j) {
        float u = s[j];
        rank += (u > v) || (u == v && j < t);
    }
    int sel = rank < KK;
    fl[t] = (unsigned char)sel;
    __syncthreads();
    int idx = 0;
    for (int j = 0; j < t; ++j) idx += fl[j];
    if (sel) {
        int m = g * KK + idx;
        perm[m] = n;
        inv[n] = m;
    } else {
        inv[n] = NT2;
    }
}

// ---------------- Gate (BN fused): h2[m] = BNReLU(z2[perm[m]]) * tanh(score) ----------------
__global__ void k_gate(const float* __restrict__ z, const float* __restrict__ scsh,
                       const float* __restrict__ score, const int* __restrict__ perm,
                       float* __restrict__ out) {
    int m = blockIdx.x, d = threadIdx.x;
    int n = perm[m];
    float v = fmaxf(z[n * DD + d] * scsh[d] + scsh[DD + d], 0.f);
    out[m * DD + d] = v * tanhf(score[n]);
}

// ---------------- Mean-pool (BN fused) + head + sigmoid ----------------
__global__ void k_final(const float* __restrict__ z, const float* __restrict__ scsh,
                        const float* __restrict__ oW, const float* __restrict__ ob,
                        float* __restrict__ out) {
    int g = blockIdx.x, t = threadIdx.x;  // 128
    float sct = scsh[t], sht = scsh[DD + t];
    float acc = 0.f;
    for (int m = 0; m < KK; ++m) acc += fmaxf(z[(g * KK + m) * DD + t] * sct + sht, 0.f);
    __shared__ float pooled[DD];
    pooled[t] = acc * (1.f / (float)KK);
    __syncthreads();
    if (t < OUTD) {
        float o = ob[t];
        for (int k = 0; k < DD; ++k) o += pooled[k] * oW[k * OUTD + t];
        out[g * OUTD + t] = 1.f / (1.f + expf(-o));
    }
}

extern "C" void kernel_launch(void* const* d_in, const int* in_sizes, int n_in,
                              void* d_out, int out_size, void* d_ws, size_t ws_size,
                              hipStream_t stream) {
    const int*   x        = (const int*)d_in[0];
    const int*   ei       = (const int*)d_in[1];
    const float* atom_emb = (const float*)d_in[4];
    const float* convW    = (const float*)d_in[6];
    const float* convb    = (const float*)d_in[7];
    const float* gam      = (const float*)d_in[8];
    const float* bet      = (const float*)d_in[9];
    const float* eps      = (const float*)d_in[10];
    const float* tw       = (const float*)d_in[11];
    const float* oW       = (const float*)d_in[12];
    const float* ob       = (const float*)d_in[13];
    float* out = (float*)d_out;

    char* p = (char*)d_ws;
    float* hA     = (float*)p; p += (size_t)NN * DD * 4;
    float* hB     = (float*)p; p += (size_t)NN * DD * 4;
    int* counts1  = (int*)p;   p += (size_t)NN * 4;
    int* off1     = (int*)p;   p += (size_t)NN * 4;
    int* cur1     = (int*)p;   p += (size_t)NN * 4;
    int* csr1     = (int*)p;   p += (size_t)EE * 4;
    int* counts2  = (int*)p;   p += (size_t)NT2 * 4;
    int* off2     = (int*)p;   p += (size_t)NT2 * 4;
    int* cur2     = (int*)p;   p += (size_t)NT2 * 4;
    int* csr2     = (int*)p;   p += (size_t)EE * 4;
    float* score  = (float*)p; p += (size_t)NN * 4;
    int* invm     = (int*)p;   p += (size_t)NN * 4;
    int* perm     = (int*)p;   p += (size_t)NT2 * 4;
    float* bnst   = (float*)p; p += (size_t)5 * 2 * DD * 4;  // 5 layers x (sum,sumsq)
    float* scshA  = (float*)p; p += (size_t)2 * DD * 4;      // layer-2 scale/shift
    float* scshB  = (float*)p; p += (size_t)2 * DD * 4;      // layer-4 scale/shift
    int* bsums    = (int*)p;   p += (size_t)256 * 4;
    float* invn   = (float*)p; p += 16;
    if ((size_t)(p - (char*)d_ws) > ws_size) return;

    const int* src = ei;
    const int* dst = ei + EE;
    const float invNN = 1.f / (float)NN;
    const float invN2 = 1.f / (float)NT2;

    hipMemsetAsync(bnst, 0, (size_t)5 * 2 * DD * 4, stream);

    // Atom encoder
    k_atom<<<NN, 128, 0, stream>>>(x, atom_emb, hA);

    // Phase-1 CSR
    hipMemsetAsync(counts1, 0, (size_t)NN * 4, stream);
    k_count<<<EE / 256, 256, 0, stream>>>(dst, counts1, EE);
    k_scanA<<<NN / 256, 256, 0, stream>>>(counts1, off1, bsums);
    k_scanB<<<1, 256, 0, stream>>>(bsums, NN / 256);
    k_scanC<<<NN / 256, 256, 0, stream>>>(off1, bsums);
    hipMemsetAsync(cur1, 0, (size_t)NN * 4, stream);
    k_place<<<EE / 256, 256, 0, stream>>>(src, dst, off1, cur1, csr1, EE);

    // Layer 0 (input raw h0)
    k_agg_f<NPGC><<<BB, 1024, 0, stream>>>(hA, bnst, gam, bet, invNN, 0, eps, 0,
                                           off1, counts1, csr1, hB);
    k_mm<<<NN / MMR, 256, 0, stream>>>(hB, convW, convb, 0, bnst + 0 * 2 * DD);
    // Layer 1 (BN layer-0 fused)
    k_agg_f<NPGC><<<BB, 1024, 0, stream>>>(hB, bnst + 0 * 2 * DD, gam + 0 * DD, bet + 0 * DD,
                                           invNN, 1, eps, 1, off1, counts1, csr1, hA);
    k_mm<<<NN / MMR, 256, 0, stream>>>(hA, convW, convb, 1, bnst + 1 * 2 * DD);
    // Layer 2 (BN layer-1 fused)
    k_agg_f<NPGC><<<BB, 1024, 0, stream>>>(hA, bnst + 1 * 2 * DD, gam + 1 * DD, bet + 1 * DD,
                                           invNN, 1, eps, 2, off1, counts1, csr1, hB);
    k_mm<<<NN / MMR, 256, 0, stream>>>(hB, convW, convb, 2, bnst + 2 * 2 * DD);

    // TopK pooling (BN layer-2 fused into score/gate)
    k_mkbn<<<1, 128, 0, stream>>>(bnst + 2 * 2 * DD, gam + 2 * DD, bet + 2 * DD, invNN, scshA);
    k_wnorm<<<1, 128, 0, stream>>>(tw, invn);
    k_score<<<NN, 128, 0, stream>>>(hB, scshA, tw, invn, score);
    k_topk<<<BB, 256, 0, stream>>>(score, invm, perm);
    k_gate<<<NT2, 128, 0, stream>>>(hB, scshA, score, perm, hA);

    // Phase-2 CSR
    hipMemsetAsync(counts2, 0, (size_t)NT2 * 4, stream);
    k_count2<<<EE / 256, 256, 0, stream>>>(src, dst, invm, counts2, EE);
    k_scanA<<<NT2 / 256, 256, 0, stream>>>(counts2, off2, bsums);
    k_scanB<<<1, 256, 0, stream>>>(bsums, NT2 / 256);
    k_scanC<<<NT2 / 256, 256, 0, stream>>>(off2, bsums);
    hipMemsetAsync(cur2, 0, (size_t)NT2 * 4, stream);
    k_place2<<<EE / 256, 256, 0, stream>>>(src, dst, invm, off2, cur2, csr2, EE);

    // Layer 3 (input raw gated h)
    k_agg_f<KK><<<BB, 1024, 0, stream>>>(hA, bnst, gam, bet, invN2, 0, eps, 3,
                                         off2, counts2, csr2, hB);
    k_mm<<<NT2 / MMR, 256, 0, stream>>>(hB, convW, convb, 3, bnst + 3 * 2 * DD);
    // Layer 4 (BN layer-3 fused)
    k_agg_f<KK><<<BB, 1024, 0, stream>>>(hB, bnst + 3 * 2 * DD, gam + 3 * DD, bet + 3 * DD,
                                         invN2, 1, eps, 4, off2, counts2, csr2, hA);
    k_mm<<<NT2 / MMR, 256, 0, stream>>>(hA, convW, convb, 4, bnst + 4 * 2 * DD);

    // Head (BN layer-4 fused)
    k_mkbn<<<1, 128, 0, stream>>>(bnst + 4 * 2 * DD, gam + 4 * DD, bet + 4 * DD, invN2, scshB);
    k_final<<<BB, 128, 0, stream>>>(hA, scshB, oW, ob, out);
}

// Round 4
// 416.490 us; speedup vs baseline: 1.9228x; 1.3460x over previous
//
#include <hip/hip_runtime.h>
#include <math.h>

#define NN   65536
#define BB   256
#define NPGC 256
#define EE   1048576
#define DD   128
#define KK   128
#define NT2  32768
#define OUTD 12
#define BN_EPS 1e-5f

typedef __attribute__((ext_vector_type(8))) short bf16x8;
typedef __attribute__((ext_vector_type(4))) float f32x4;

__device__ __forceinline__ unsigned short bf16_rne(float v) {
    unsigned u = __float_as_uint(v);
    unsigned r = u + 0x7FFFu + ((u >> 16) & 1u);
    return (unsigned short)(r >> 16);
}

// ---------------- Atom encoder ----------------
__global__ void k_atom(const int* __restrict__ x, const float* __restrict__ emb,
                       float* __restrict__ h) {
    int n = blockIdx.x, d = threadIdx.x;
    __shared__ int xr[9];
    if (d < 9) xr[d] = x[n * 9 + d];
    __syncthreads();
    float acc = 0.f;
#pragma unroll
    for (int f = 0; f < 9; ++f) acc += emb[(f * 128 + xr[f]) * DD + d];
    h[n * DD + d] = acc;
}

// ---------------- W prep: transpose + split f32 -> bf16 hi/lo, [layer][n][k] ----------------
__global__ void k_prepw(const float* __restrict__ Wg, unsigned short* __restrict__ wtHi,
                        unsigned short* __restrict__ wtLo) {
    int b = blockIdx.x;            // 0..639
    int l = b >> 7, n = b & 127;
    int k = threadIdx.x;           // 128
    float v = Wg[l * 16384 + k * 128 + n];
    unsigned short hb = bf16_rne(v);
    float hf = __uint_as_float((unsigned)hb << 16);
    unsigned short lb = bf16_rne(v - hf);
    wtHi[l * 16384 + n * 128 + k] = hb;
    wtLo[l * 16384 + n * 128 + k] = lb;
}

// ---------------- CSR build ----------------
__global__ void k_count(const int* __restrict__ dst, int* __restrict__ counts, int n) {
    int i = blockIdx.x * blockDim.x + threadIdx.x;
    if (i < n) atomicAdd(&counts[dst[i]], 1);
}

__global__ void k_scanA(const int* __restrict__ in, int* __restrict__ out, int* __restrict__ bs) {
    __shared__ int s[256];
    int t = threadIdx.x, i = blockIdx.x * 256 + t;
    int v = in[i];
    s[t] = v; __syncthreads();
    for (int d = 1; d < 256; d <<= 1) {
        int u = (t >= d) ? s[t - d] : 0;
        __syncthreads();
        s[t] += u;
        __syncthreads();
    }
    out[i] = s[t] - v;
    if (t == 255) bs[blockIdx.x] = s[255];
}

__global__ void k_scanB(int* bs, int nb) {
    __shared__ int s[256];
    int t = threadIdx.x;
    int v = (t < nb) ? bs[t] : 0;
    s[t] = v; __syncthreads();
    for (int d = 1; d < 256; d <<= 1) {
        int u = (t >= d) ? s[t - d] : 0;
        __syncthreads();
        s[t] += u;
        __syncthreads();
    }
    if (t < nb) bs[t] = s[t] - v;
}

__global__ void k_scanC(int* out, const int* __restrict__ bs) {
    int i = blockIdx.x * 256 + threadIdx.x;
    out[i] += bs[blockIdx.x];
}

__global__ void k_place(const int* __restrict__ src, const int* __restrict__ dst,
                        const int* __restrict__ off, int* __restrict__ cur,
                        int* __restrict__ csr, int n) {
    int i = blockIdx.x * blockDim.x + threadIdx.x;
    if (i < n) {
        int d = dst[i];
        int slot = off[d] + atomicAdd(&cur[d], 1);
        csr[slot] = src[i];
    }
}

__global__ void k_count2(const int* __restrict__ src, const int* __restrict__ dst,
                         const int* __restrict__ inv, int* __restrict__ counts, int n) {
    int i = blockIdx.x * blockDim.x + threadIdx.x;
    if (i < n) {
        int s = inv[src[i]], d = inv[dst[i]];
        if (s < NT2 && d < NT2) atomicAdd(&counts[d], 1);
    }
}

__global__ void k_place2(const int* __restrict__ src, const int* __restrict__ dst,
                         const int* __restrict__ inv, const int* __restrict__ off,
                         int* __restrict__ cur, int* __restrict__ csr, int n) {
    int i = blockIdx.x * blockDim.x + threadIdx.x;
    if (i < n) {
        int s = inv[src[i]], d = inv[dst[i]];
        if (s < NT2 && d < NT2) {
            int slot = off[d] + atomicAdd(&cur[d], 1);
            csr[slot] = s;
        }
    }
}

// ---------------- Fused BN(prev)+ReLU + GIN aggregate, one graph per block ----------------
template<int NPG_T>
__global__ __launch_bounds__(1024) void k_agg_f(
    const float* __restrict__ zin, const float* __restrict__ stats,
    const float* __restrict__ gamL, const float* __restrict__ betL,
    float invRows, int doBN,
    const float* __restrict__ epsArr, int layer,
    const int* __restrict__ off, const int* __restrict__ deg,
    const int* __restrict__ csr, float* __restrict__ aout)
{
    __shared__ float A[NPG_T * DD];
    __shared__ int nbl[4096];
    __shared__ float sc[DD], sh[DD];
    const int g = blockIdx.x;
    const int t = threadIdx.x;
    const int nbase = g * NPG_T;

    if (doBN && t < DD) {
        float mu = stats[t] * invRows;
        float var = stats[DD + t] * invRows - mu * mu;
        float istd = rsqrtf(var + BN_EPS);
        float ga = gamL[t], be = betL[t];
        sc[t] = ga * istd;
        sh[t] = be - mu * ga * istd;
    }
    const int e0 = off[nbase];
    const int eCnt = off[nbase + NPG_T - 1] + deg[nbase + NPG_T - 1] - e0;
    for (int i = t; i < eCnt; i += 1024) nbl[i] = csr[e0 + i] - nbase;
    __syncthreads();

    const float4* zin4 = (const float4*)(zin + (size_t)nbase * DD);
    float4* A4 = (float4*)A;
    for (int i = t; i < NPG_T * DD / 4; i += 1024) {
        float4 v = zin4[i];
        if (doBN) {
            int c = (i << 2) & (DD - 1);
            v.x = fmaxf(v.x * sc[c] + sh[c], 0.f);
            v.y = fmaxf(v.y * sc[c + 1] + sh[c + 1], 0.f);
            v.z = fmaxf(v.z * sc[c + 2] + sh[c + 2], 0.f);
            v.w = fmaxf(v.w * sc[c + 3] + sh[c + 3], 0.f);
        }
        A4[i] = v;
    }
    __syncthreads();

    const float opEps = 1.f + epsArr[layer];
    const int wave = t >> 6, lane = t & 63;
    const float2* A2 = (const float2*)A;
    constexpr int NPW = NPG_T / 16;
#pragma unroll
    for (int i = 0; i < NPW; ++i) {
        int node = wave * NPW + i;
        int gnode = nbase + node;
        int st = off[gnode] - e0;
        int dg = deg[gnode];
        float2 self = A2[node * 64 + lane];
        float ax = self.x * opEps, ay = self.y * opEps;
        int j = 0;
        for (; j + 3 < dg; j += 4) {
            int n0 = nbl[st + j], n1 = nbl[st + j + 1], n2 = nbl[st + j + 2], n3 = nbl[st + j + 3];
            float2 v0 = A2[n0 * 64 + lane];
            float2 v1 = A2[n1 * 64 + lane];
            float2 v2 = A2[n2 * 64 + lane];
            float2 v3 = A2[n3 * 64 + lane];
            ax += v0.x + v1.x + v2.x + v3.x;
            ay += v0.y + v1.y + v2.y + v3.y;
        }
        for (; j < dg; ++j) {
            int nb = nbl[st + j];
            float2 v = A2[nb * 64 + lane];
            ax += v.x; ay += v.y;
        }
        float2 o; o.x = ax; o.y = ay;
        ((float2*)aout)[(size_t)gnode * 64 + lane] = o;
    }
}

// ---------------- MFMA split-bf16 matmul (in-place) + fused BN stats ----------------
// z[64xM-tile] = z @ W^T(prepared) + b; error ~2^-16 via hi/lo 3-product.
__global__ __launch_bounds__(256) void k_mm(float* __restrict__ z,
    const unsigned short* __restrict__ wtHi, const unsigned short* __restrict__ wtLo,
    const float* __restrict__ bg, int layer, float* __restrict__ stats) {
    __shared__ unsigned short aHi[64 * 128], aLo[64 * 128];   // 16KB each, swizzled
    __shared__ unsigned short wHi[128 * 32], wLo[128 * 32];   // 8KB each, swizzled
    const int t = threadIdx.x;
    const int row0 = blockIdx.x * 64;
    const unsigned short* WH = wtHi + layer * 16384;
    const unsigned short* WL = wtLo + layer * 16384;

    // ---- stage A tile with f32 -> (hi, lo) bf16 split; swizzle (r&7)<<3 ----
    {
        int r = t >> 2, kq = (t & 3) * 32;
        const float4* srcp = (const float4*)&z[(row0 + r) * 128 + kq];
        float4 v[8];
#pragma unroll
        for (int i = 0; i < 8; ++i) v[i] = srcp[i];
#pragma unroll
        for (int i = 0; i < 4; ++i) {
            float e[8] = {v[2*i].x, v[2*i].y, v[2*i].z, v[2*i].w,
                          v[2*i+1].x, v[2*i+1].y, v[2*i+1].z, v[2*i+1].w};
            bf16x8 h8, l8;
#pragma unroll
            for (int j = 0; j < 8; ++j) {
                unsigned short hb = bf16_rne(e[j]);
                float hf = __uint_as_float((unsigned)hb << 16);
                h8[j] = (short)hb;
                l8[j] = (short)bf16_rne(e[j] - hf);
            }
            int idx = (r * 128 + kq + i * 8) ^ ((r & 7) << 3);
            *(bf16x8*)&aHi[idx] = h8;
            *(bf16x8*)&aLo[idx] = l8;
        }
    }

    const int wv = t >> 6, l = t & 63;
    const int la = l & 15, kg = l >> 4;
    const int rowa = wv * 16 + la;
    const int aXor = (rowa & 7) << 3;
    f32x4 acc[8] = {};

    for (int c = 0; c < 4; ++c) {
        __syncthreads();
        // stage W chunk c: [128 n][32 k] hi/lo, swizzle ((n>>1)&3)<<3
        {
            int n = t >> 1, kh = (t & 1) * 16;
            const bf16x8* gh = (const bf16x8*)&WH[n * 128 + c * 32 + kh];
            const bf16x8* gl = (const bf16x8*)&WL[n * 128 + c * 32 + kh];
            bf16x8 h0 = gh[0], h1 = gh[1], l0 = gl[0], l1 = gl[1];
            int swz = ((n >> 1) & 3) << 3;
            int i0 = (n * 32 + kh) ^ swz;
            int i1 = (n * 32 + kh + 8) ^ swz;
            *(bf16x8*)&wHi[i0] = h0; *(bf16x8*)&wHi[i1] = h1;
            *(bf16x8*)&wLo[i0] = l0; *(bf16x8*)&wLo[i1] = l1;
        }
        __syncthreads();
        int ai = (rowa * 128 + c * 32 + kg * 8) ^ aXor;
        bf16x8 ah = *(const bf16x8*)&aHi[ai];
        bf16x8 al = *(const bf16x8*)&aLo[ai];
#pragma unroll
        for (int gi = 0; gi < 8; ++gi) {
            int n = gi * 16 + la;
            int bi = (n * 32 + kg * 8) ^ (((n >> 1) & 3) << 3);
            bf16x8 bh = *(const bf16x8*)&wHi[bi];
            bf16x8 bl = *(const bf16x8*)&wLo[bi];
            acc[gi] = __builtin_amdgcn_mfma_f32_16x16x32_bf16(ah, bh, acc[gi], 0, 0, 0);
            acc[gi] = __builtin_amdgcn_mfma_f32_16x16x32_bf16(ah, bl, acc[gi], 0, 0, 0);
            acc[gi] = __builtin_amdgcn_mfma_f32_16x16x32_bf16(al, bh, acc[gi], 0, 0, 0);
        }
    }

    // ---- epilogue: bias add, store, BN partial stats (reuse LDS) ----
    __syncthreads();
    float* partS = (float*)aHi;   // [16][128]
    float* partQ = (float*)aLo;
    const float* bias = bg + layer * 128;
    const int rg = wv * 4 + kg;
    const int rbase = row0 + wv * 16 + kg * 4;
#pragma unroll
    for (int gi = 0; gi < 8; ++gi) {
        int col = gi * 16 + la;
        float bv = bias[col];
        float s = 0.f, q = 0.f;
#pragma unroll
        for (int r = 0; r < 4; ++r) {
            float o = acc[gi][r] + bv;
            z[(rbase + r) * 128 + col] = o;
            s += o; q += o * o;
        }
        partS[rg * 128 + col] = s;
        partQ[rg * 128 + col] = q;
    }
    __syncthreads();
    if (t < 128) {
        float s = 0.f, q = 0.f;
#pragma unroll
        for (int i = 0; i < 16; ++i) { s += partS[i * 128 + t]; q += partQ[i * 128 + t]; }
        atomicAdd(&stats[t], s);
        atomicAdd(&stats[DD + t], q);
    }
}

// ---------------- BN scale/shift materialization (tiny) ----------------
__global__ void k_mkbn(const float* __restrict__ stats, const float* __restrict__ gamL,
                       const float* __restrict__ betL, float invRows, float* __restrict__ scsh) {
    int t = threadIdx.x;  // 128
    float mu = stats[t] * invRows;
    float var = stats[DD + t] * invRows - mu * mu;
    float istd = rsqrtf(var + BN_EPS);
    float ga = gamL[t], be = betL[t];
    scsh[t] = ga * istd;
    scsh[DD + t] = be - mu * ga * istd;
}

// ---------------- TopK scoring (BN fused) ----------------
__global__ void k_wnorm(const float* __restrict__ w, float* __restrict__ invn) {
    __shared__ float s[128];
    int t = threadIdx.x;
    float v = w[t];
    s[t] = v * v; __syncthreads();
    for (int d = 64; d > 0; d >>= 1) {
        if (t < d) s[t] += s[t + d];
        __syncthreads();
    }
    if (t == 0) *invn = rsqrtf(s[0]);
}

__global__ void k_score(const float* __restrict__ z, const float* __restrict__ scsh,
                        const float* __restrict__ w, const float* __restrict__ invn,
                        float* __restrict__ score) {
    int n = blockIdx.x, t = threadIdx.x;  // 128
    float v = fmaxf(z[n * DD + t] * scsh[t] + scsh[DD + t], 0.f);
    float p = v * w[t];
    for (int off = 32; off > 0; off >>= 1) p += __shfl_down(p, off);
    __shared__ float s2[2];
    if ((t & 63) == 0) s2[t >> 6] = p;
    __syncthreads();
    if (t == 0) score[n] = (s2[0] + s2[1]) * (*invn);
}

// ---------------- TopK selection (rank counting; set-equivalent to reference) ----------------
__global__ void k_topk(const float* __restrict__ score, int* __restrict__ inv,
                       int* __restrict__ perm) {
    int g = blockIdx.x, t = threadIdx.x;  // 256
    __shared__ float s[NPGC];
    __shared__ unsigned char fl[NPGC];
    int n = g * NPGC + t;
    float v = score[n];
    s[t] = v; __syncthreads();
    int rank = 0;
    for (int j = 0; j < NPGC; ++j) {
        float u = s[j];
        rank += (u > v) || (u == v && j < t);
    }
    int sel = rank < KK;
    fl[t] = (unsigned char)sel;
    __syncthreads();
    int idx = 0;
    for (int j = 0; j < t; ++j) idx += fl[j];
    if (sel) {
        int m = g * KK + idx;
        perm[m] = n;
        inv[n] = m;
    } else {
        inv[n] = NT2;
    }
}

// ---------------- Gate (BN fused) ----------------
__global__ void k_gate(const float* __restrict__ z, const float* __restrict__ scsh,
                       const float* __restrict__ score, const int* __restrict__ perm,
                       float* __restrict__ out) {
    int m = blockIdx.x, d = threadIdx.x;
    int n = perm[m];
    float v = fmaxf(z[n * DD + d] * scsh[d] + scsh[DD + d], 0.f);
    out[m * DD + d] = v * tanhf(score[n]);
}

// ---------------- Mean-pool (BN fused) + head + sigmoid ----------------
__global__ void k_final(const float* __restrict__ z, const float* __restrict__ scsh,
                        const float* __restrict__ oW, const float* __restrict__ ob,
                        float* __restrict__ out) {
    int g = blockIdx.x, t = threadIdx.x;  // 128
    float sct = scsh[t], sht = scsh[DD + t];
    float acc = 0.f;
    for (int m = 0; m < KK; ++m) acc += fmaxf(z[(g * KK + m) * DD + t] * sct + sht, 0.f);
    __shared__ float pooled[DD];
    pooled[t] = acc * (1.f / (float)KK);
    __syncthreads();
    if (t < OUTD) {
        float o = ob[t];
        for (int k = 0; k < DD; ++k) o += pooled[k] * oW[k * OUTD + t];
        out[g * OUTD + t] = 1.f / (1.f + expf(-o));
    }
}

extern "C" void kernel_launch(void* const* d_in, const int* in_sizes, int n_in,
                              void* d_out, int out_size, void* d_ws, size_t ws_size,
                              hipStream_t stream) {
    const int*   x        = (const int*)d_in[0];
    const int*   ei       = (const int*)d_in[1];
    const float* atom_emb = (const float*)d_in[4];
    const float* convW    = (const float*)d_in[6];
    const float* convb    = (const float*)d_in[7];
    const float* gam      = (const float*)d_in[8];
    const float* bet      = (const float*)d_in[9];
    const float* eps      = (const float*)d_in[10];
    const float* tw       = (const float*)d_in[11];
    const float* oW       = (const float*)d_in[12];
    const float* ob       = (const float*)d_in[13];
    float* out = (float*)d_out;

    char* p = (char*)d_ws;
    float* hA     = (float*)p; p += (size_t)NN * DD * 4;
    float* hB     = (float*)p; p += (size_t)NN * DD * 4;
    int* counts1  = (int*)p;   p += (size_t)NN * 4;
    int* off1     = (int*)p;   p += (size_t)NN * 4;
    int* cur1     = (int*)p;   p += (size_t)NN * 4;
    int* csr1     = (int*)p;   p += (size_t)EE * 4;
    int* counts2  = (int*)p;   p += (size_t)NT2 * 4;
    int* off2     = (int*)p;   p += (size_t)NT2 * 4;
    int* cur2     = (int*)p;   p += (size_t)NT2 * 4;
    int* csr2     = (int*)p;   p += (size_t)EE * 4;
    float* score  = (float*)p; p += (size_t)NN * 4;
    int* invm     = (int*)p;   p += (size_t)NN * 4;
    int* perm     = (int*)p;   p += (size_t)NT2 * 4;
    float* bnst   = (float*)p; p += (size_t)5 * 2 * DD * 4;
    float* scshA  = (float*)p; p += (size_t)2 * DD * 4;
    float* scshB  = (float*)p; p += (size_t)2 * DD * 4;
    int* bsums    = (int*)p;   p += (size_t)256 * 4;
    float* invn   = (float*)p; p += 16;
    unsigned short* wtHi = (unsigned short*)p; p += (size_t)5 * DD * DD * 2;
    unsigned short* wtLo = (unsigned short*)p; p += (size_t)5 * DD * DD * 2;
    if ((size_t)(p - (char*)d_ws) > ws_size) return;

    const int* src = ei;
    const int* dst = ei + EE;
    const float invNN = 1.f / (float)NN;
    const float invN2 = 1.f / (float)NT2;

    hipMemsetAsync(bnst, 0, (size_t)5 * 2 * DD * 4, stream);
    k_prepw<<<640, 128, 0, stream>>>(convW, wtHi, wtLo);

    // Atom encoder
    k_atom<<<NN, 128, 0, stream>>>(x, atom_emb, hA);

    // Phase-1 CSR
    hipMemsetAsync(counts1, 0, (size_t)NN * 4, stream);
    k_count<<<EE / 256, 256, 0, stream>>>(dst, counts1, EE);
    k_scanA<<<NN / 256, 256, 0, stream>>>(counts1, off1, bsums);
    k_scanB<<<1, 256, 0, stream>>>(bsums, NN / 256);
    k_scanC<<<NN / 256, 256, 0, stream>>>(off1, bsums);
    hipMemsetAsync(cur1, 0, (size_t)NN * 4, stream);
    k_place<<<EE / 256, 256, 0, stream>>>(src, dst, off1, cur1, csr1, EE);

    // Layer 0
    k_agg_f<NPGC><<<BB, 1024, 0, stream>>>(hA, bnst, gam, bet, invNN, 0, eps, 0,
                                           off1, counts1, csr1, hB);
    k_mm<<<NN / 64, 256, 0, stream>>>(hB, wtHi, wtLo, convb, 0, bnst + 0 * 2 * DD);
    // Layer 1
    k_agg_f<NPGC><<<BB, 1024, 0, stream>>>(hB, bnst + 0 * 2 * DD, gam + 0 * DD, bet + 0 * DD,
                                           invNN, 1, eps, 1, off1, counts1, csr1, hA);
    k_mm<<<NN / 64, 256, 0, stream>>>(hA, wtHi, wtLo, convb, 1, bnst + 1 * 2 * DD);
    // Layer 2
    k_agg_f<NPGC><<<BB, 1024, 0, stream>>>(hA, bnst + 1 * 2 * DD, gam + 1 * DD, bet + 1 * DD,
                                           invNN, 1, eps, 2, off1, counts1, csr1, hB);
    k_mm<<<NN / 64, 256, 0, stream>>>(hB, wtHi, wtLo, convb, 2, bnst + 2 * 2 * DD);

    // TopK pooling (BN layer-2 fused)
    k_mkbn<<<1, 128, 0, stream>>>(bnst + 2 * 2 * DD, gam + 2 * DD, bet + 2 * DD, invNN, scshA);
    k_wnorm<<<1, 128, 0, stream>>>(tw, invn);
    k_score<<<NN, 128, 0, stream>>>(hB, scshA, tw, invn, score);
    k_topk<<<BB, 256, 0, stream>>>(score, invm, perm);
    k_gate<<<NT2, 128, 0, stream>>>(hB, scshA, score, perm, hA);

    // Phase-2 CSR
    hipMemsetAsync(counts2, 0, (size_t)NT2 * 4, stream);
    k_count2<<<EE / 256, 256, 0, stream>>>(src, dst, invm, counts2, EE);
    k_scanA<<<NT2 / 256, 256, 0, stream>>>(counts2, off2, bsums);
    k_scanB<<<1, 256, 0, stream>>>(bsums, NT2 / 256);
    k_scanC<<<NT2 / 256, 256, 0, stream>>>(off2, bsums);
    hipMemsetAsync(cur2, 0, (size_t)NT2 * 4, stream);
    k_place2<<<EE / 256, 256, 0, stream>>>(src, dst, invm, off2, cur2, csr2, EE);

    // Layer 3
    k_agg_f<KK><<<BB, 1024, 0, stream>>>(hA, bnst, gam, bet, invN2, 0, eps, 3,
                                         off2, counts2, csr2, hB);
    k_mm<<<NT2 / 64, 256, 0, stream>>>(hB, wtHi, wtLo, convb, 3, bnst + 3 * 2 * DD);
    // Layer 4
    k_agg_f<KK><<<BB, 1024, 0, stream>>>(hB, bnst + 3 * 2 * DD, gam + 3 * DD, bet + 3 * DD,
                                         invN2, 1, eps, 4, off2, counts2, csr2, hA);
    k_mm<<<NT2 / 64, 256, 0, stream>>>(hA, wtHi, wtLo, convb, 4, bnst + 4 * 2 * DD);

    // Head (BN layer-4 fused)
    k_mkbn<<<1, 128, 0, stream>>>(bnst + 4 * 2 * DD, gam + 4 * DD, bet + 4 * DD, invN2, scshB);
    k_final<<<BB, 128, 0, stream>>>(hA, scshB, oW, ob, out);
}

// Round 5
// 362.116 us; speedup vs baseline: 2.2115x; 1.1502x over previous
//
#include <hip/hip_runtime.h>
#include <hip/hip_cooperative_groups.h>
#include <math.h>

namespace cg = cooperative_groups;

#define NN   65536
#define BB   256
#define NPGC 256
#define EE   1048576
#define DD   128
#define KK   128
#define NT2  32768
#define OUTD 12
#define BN_EPS 1e-5f
#define INV_N1 (1.f / 65536.f)
#define INV_N2 (1.f / 32768.f)

typedef __attribute__((ext_vector_type(8))) short bf16x8;
typedef __attribute__((ext_vector_type(4))) float f32x4;

__device__ __forceinline__ unsigned short bf16_rne(float v) {
    unsigned u = __float_as_uint(v);
    unsigned r = u + 0x7FFFu + ((u >> 16) & 1u);
    return (unsigned short)(r >> 16);
}

// ---------------- W prep: transpose + split f32 -> bf16 hi/lo, [layer][n][k] ----------------
__global__ void k_prepw(const float* __restrict__ Wg, unsigned short* __restrict__ wtHi,
                        unsigned short* __restrict__ wtLo) {
    int b = blockIdx.x;            // 0..639
    int l = b >> 7, n = b & 127;
    int k = threadIdx.x;           // 128
    float v = Wg[l * 16384 + k * 128 + n];
    unsigned short hb = bf16_rne(v);
    float hf = __uint_as_float((unsigned)hb << 16);
    unsigned short lb = bf16_rne(v - hf);
    wtHi[l * 16384 + n * 128 + k] = hb;
    wtLo[l * 16384 + n * 128 + k] = lb;
}

// ---------------- The whole network: one graph per block, h resident in LDS ----------------
__global__ __launch_bounds__(1024) void k_mega(
    const int* __restrict__ x, const int* __restrict__ ei,
    const float* __restrict__ emb,
    const unsigned short* __restrict__ wtHi, const unsigned short* __restrict__ wtLo,
    const float* __restrict__ bg, const float* __restrict__ gam,
    const float* __restrict__ bet, const float* __restrict__ epsArr,
    const float* __restrict__ tw, const float* __restrict__ oW,
    const float* __restrict__ ob, float* __restrict__ bnst,
    float* __restrict__ out)
{
    cg::grid_group grid = cg::this_grid();

    __shared__ __align__(16) unsigned char U[131072];      // h f32 (256x128) OR aHi/aLo bf16
    __shared__ __align__(16) unsigned short wS[2][4096];   // W chunk hi/lo (16KB); aliased by xr early
    __shared__ unsigned char csr8[4096];
    __shared__ int offl[257];
    __shared__ int curl[256];
    __shared__ int sscan[256];
    __shared__ float score[256];
    __shared__ float scsh[256];    // sc[0..127], sh[128..255]
    __shared__ float wlds[128];
    __shared__ float pooled[128];
    __shared__ unsigned char newid[256];
    __shared__ unsigned char perml[128];
    __shared__ unsigned char flg[256];
    __shared__ float invn_s;

    float* hF = (float*)U;
    float2* hF2 = (float2*)U;
    unsigned short* aHi = (unsigned short*)U;
    unsigned short* aLo = (unsigned short*)(U + 65536);

    const int g = blockIdx.x;
    const int t = threadIdx.x;
    const int wv = t >> 6, l = t & 63;
    const int la = l & 15, kg = l >> 4;
    const int nbase = g * NPGC;
    const int* srcg = ei + g * 4096;
    const int* dstg = ei + EE + g * 4096;

    // ================= atom encoder =================
    {
        int* xr = (int*)wS;  // 2304 ints, fits in 16KB
        for (int i = t; i < NPGC * 9; i += 1024) xr[i] = x[nbase * 9 + i];
        __syncthreads();
        int n = t >> 2, cq = (t & 3) << 5;
        f32x4 a8[8] = {};
#pragma unroll
        for (int f = 0; f < 9; ++f) {
            const f32x4* ep = (const f32x4*)&emb[(size_t)((f << 7) + xr[n * 9 + f]) * DD + cq];
#pragma unroll
            for (int q = 0; q < 8; ++q) a8[q] += ep[q];
        }
        f32x4* hq = (f32x4*)&hF[n * DD + cq];
#pragma unroll
        for (int q = 0; q < 8; ++q) hq[q] = a8[q];
    }

    // ================= CSR1 (block-local) =================
    for (int i = t; i < 256; i += 1024) curl[i] = 0;
    __syncthreads();
    for (int i = t; i < 4096; i += 1024) atomicAdd(&curl[dstg[i] - nbase], 1);
    __syncthreads();
    if (t < 256) sscan[t] = curl[t];
    __syncthreads();
    for (int d = 1; d < 256; d <<= 1) {
        int v = (t < 256 && t >= d) ? sscan[t - d] : 0;
        __syncthreads();
        if (t < 256) sscan[t] += v;
        __syncthreads();
    }
    if (t < 256) offl[t] = sscan[t] - curl[t];
    if (t == 0) offl[256] = 4096;
    for (int i = t; i < 256; i += 1024) curl[i] = 0;
    __syncthreads();
    for (int i = t; i < 4096; i += 1024) {
        int d = dstg[i] - nbase;
        int slot = offl[d] + atomicAdd(&curl[d], 1);
        csr8[slot] = (unsigned char)(srcg[i] - nbase);
    }
    __syncthreads();

    // ================= phase-1: 3 GIN layers on 256 nodes =================
    for (int L = 0; L < 3; ++L) {
        const float opEps = 1.f + epsArr[L];
        // ---- aggregate into registers (wave wv owns nodes wv*16..+15; lane = 2 channels) ----
        float agx[16], agy[16];
#pragma unroll
        for (int i = 0; i < 16; ++i) {
            int node = wv * 16 + i;
            int st = offl[node], en = offl[node + 1];
            float2 a = hF2[node * 64 + l];
            float ax = a.x * opEps, ay = a.y * opEps;
            int j = st;
            for (; j + 3 < en; j += 4) {
                int n0 = csr8[j], n1 = csr8[j + 1], n2 = csr8[j + 2], n3 = csr8[j + 3];
                float2 v0 = hF2[n0 * 64 + l];
                float2 v1 = hF2[n1 * 64 + l];
                float2 v2 = hF2[n2 * 64 + l];
                float2 v3 = hF2[n3 * 64 + l];
                ax += v0.x + v1.x + v2.x + v3.x;
                ay += v0.y + v1.y + v2.y + v3.y;
            }
            for (; j < en; ++j) {
                float2 v = hF2[csr8[j] * 64 + l];
                ax += v.x; ay += v.y;
            }
            agx[i] = ax; agy[i] = ay;
        }
        __syncthreads();
        // ---- overwrite union with swizzled bf16 hi/lo A tiles ----
#pragma unroll
        for (int i = 0; i < 16; ++i) {
            int node = wv * 16 + i;
            int idx = (node * DD + l * 2) ^ ((node & 7) << 3);
            unsigned short hx = bf16_rne(agx[i]);
            unsigned short hy = bf16_rne(agy[i]);
            float rx = agx[i] - __uint_as_float((unsigned)hx << 16);
            float ry = agy[i] - __uint_as_float((unsigned)hy << 16);
            *(unsigned*)&aHi[idx] = (unsigned)hx | ((unsigned)hy << 16);
            *(unsigned*)&aLo[idx] = (unsigned)bf16_rne(rx) | ((unsigned)bf16_rne(ry) << 16);
        }
        // ---- MFMA: 16 waves x 16-row stripes, 8 col groups, split-bf16 3 products ----
        const unsigned short* WH = wtHi + L * 16384;
        const unsigned short* WL = wtLo + L * 16384;
        f32x4 acc[8] = {};
        const int rowa = wv * 16 + la;
        const int aXor = (rowa & 7) << 3;
        for (int c = 0; c < 4; ++c) {
            __syncthreads();
            {
                int e0 = (t & 511) * 8;
                int n = e0 >> 5, kk = e0 & 31;
                int de = e0 ^ (((n >> 1) & 3) << 3);
                const bf16x8* gsrc = (const bf16x8*)((t < 512 ? WH : WL) + n * DD + c * 32 + kk);
                *(bf16x8*)&wS[t >> 9][de] = *gsrc;
            }
            __syncthreads();
            int ai = (rowa * DD + c * 32 + kg * 8) ^ aXor;
            bf16x8 ah = *(const bf16x8*)&aHi[ai];
            bf16x8 al = *(const bf16x8*)&aLo[ai];
#pragma unroll
            for (int gi = 0; gi < 8; ++gi) {
                int n = gi * 16 + la;
                int bi = (n * 32 + kg * 8) ^ (((n >> 1) & 3) << 3);
                bf16x8 bh = *(const bf16x8*)&wS[0][bi];
                bf16x8 bl = *(const bf16x8*)&wS[1][bi];
                acc[gi] = __builtin_amdgcn_mfma_f32_16x16x32_bf16(ah, bh, acc[gi], 0, 0, 0);
                acc[gi] = __builtin_amdgcn_mfma_f32_16x16x32_bf16(ah, bl, acc[gi], 0, 0, 0);
                acc[gi] = __builtin_amdgcn_mfma_f32_16x16x32_bf16(al, bh, acc[gi], 0, 0, 0);
            }
        }
        __syncthreads();
        // ---- bias + block-partial BN stats (union reused as scratch) ----
        float* partS = (float*)U;
        float* partQ = (float*)(U + 8192);
#pragma unroll
        for (int gi = 0; gi < 8; ++gi) {
            int col = gi * 16 + la;
            float bv = bg[L * DD + col];
            float s = 0.f, q = 0.f;
#pragma unroll
            for (int r = 0; r < 4; ++r) {
                float o = acc[gi][r] + bv;
                acc[gi][r] = o;
                s += o; q += o * o;
            }
            s += __shfl_xor(s, 16); s += __shfl_xor(s, 32);
            q += __shfl_xor(q, 16); q += __shfl_xor(q, 32);
            if (kg == 0) { partS[wv * DD + col] = s; partQ[wv * DD + col] = q; }
        }
        __syncthreads();
        if (t < DD) {
            float s = 0.f, q = 0.f;
#pragma unroll
            for (int i = 0; i < 16; ++i) { s += partS[i * DD + t]; q += partQ[i * DD + t]; }
            atomicAdd(&bnst[L * 256 + t], s);
            atomicAdd(&bnst[L * 256 + DD + t], q);
        }
        grid.sync();
        if (t < DD) {
            float s = __hip_atomic_load(&bnst[L * 256 + t], __ATOMIC_RELAXED, __HIP_MEMORY_SCOPE_AGENT);
            float q = __hip_atomic_load(&bnst[L * 256 + DD + t], __ATOMIC_RELAXED, __HIP_MEMORY_SCOPE_AGENT);
            float mu = s * INV_N1;
            float var = q * INV_N1 - mu * mu;
            float istd = rsqrtf(var + BN_EPS);
            float ga = gam[L * DD + t], be = bet[L * DD + t];
            scsh[t] = ga * istd;
            scsh[DD + t] = be - mu * ga * istd;
        }
        __syncthreads();
        // ---- BN apply + ReLU -> h f32 back into union ----
#pragma unroll
        for (int gi = 0; gi < 8; ++gi) {
            int col = gi * 16 + la;
            float sc = scsh[col], sh = scsh[DD + col];
#pragma unroll
            for (int r = 0; r < 4; ++r) {
                int row = wv * 16 + kg * 4 + r;
                hF[row * DD + col] = fmaxf(acc[gi][r] * sc + sh, 0.f);
            }
        }
        __syncthreads();
    }

    // ================= score / top-k / gate (block-local) =================
    if (t < DD) wlds[t] = tw[t];
    __syncthreads();
    if (t < DD) score[t] = wlds[t] * wlds[t];
    __syncthreads();
    for (int d = 64; d > 0; d >>= 1) {
        if (t < d) score[t] += score[t + d];
        __syncthreads();
    }
    if (t == 0) invn_s = rsqrtf(score[0]);
    __syncthreads();
    {
        float wx = wlds[l * 2], wy = wlds[l * 2 + 1];
        for (int i = 0; i < 16; ++i) {
            int node = wv * 16 + i;
            float2 a = hF2[node * 64 + l];
            float p = a.x * wx + a.y * wy;
            p += __shfl_xor(p, 32); p += __shfl_xor(p, 16); p += __shfl_xor(p, 8);
            p += __shfl_xor(p, 4);  p += __shfl_xor(p, 2);  p += __shfl_xor(p, 1);
            if (l == 0) score[node] = p * invn_s;
        }
    }
    __syncthreads();
    if (t < 256) {
        float v = score[t];
        int rank = 0;
        for (int j = 0; j < 256; ++j) {
            float u = score[j];
            rank += (u > v) || (u == v && j < t);
        }
        int sel = rank < KK ? 1 : 0;
        flg[t] = (unsigned char)sel;
        sscan[t] = sel;
    }
    __syncthreads();
    for (int d = 1; d < 256; d <<= 1) {
        int v = (t < 256 && t >= d) ? sscan[t - d] : 0;
        __syncthreads();
        if (t < 256) sscan[t] += v;
        __syncthreads();
    }
    if (t < 256) {
        if (flg[t]) {
            int m = sscan[t] - 1;
            newid[t] = (unsigned char)m;
            perml[m] = (unsigned char)t;
        } else {
            newid[t] = 0xFF;
        }
    }
    __syncthreads();
    // gate: 8 threads per kept row, 16 channels each; regs carry across the overwrite
    {
        int m = t >> 3, cs = (t & 7) << 4;
        int src = perml[m];
        float tg = tanhf(score[src]);
        f32x4 gv[4];
#pragma unroll
        for (int q = 0; q < 4; ++q) {
            gv[q] = ((const f32x4*)&hF[src * DD + cs])[q];
            gv[q].x *= tg; gv[q].y *= tg; gv[q].z *= tg; gv[q].w *= tg;
        }
        __syncthreads();
#pragma unroll
        for (int q = 0; q < 4; ++q) ((f32x4*)&hF[m * DD + cs])[q] = gv[q];
    }
    __syncthreads();

    // ================= CSR2 (kept edges, block-local) =================
    for (int i = t; i < 256; i += 1024) curl[i] = 0;
    __syncthreads();
    for (int i = t; i < 4096; i += 1024) {
        int sn = newid[srcg[i] - nbase], dn = newid[dstg[i] - nbase];
        if (sn != 255 && dn != 255) atomicAdd(&curl[dn], 1);
    }
    __syncthreads();
    if (t < 256) sscan[t] = curl[t];
    __syncthreads();
    for (int d = 1; d < 256; d <<= 1) {
        int v = (t < 256 && t >= d) ? sscan[t - d] : 0;
        __syncthreads();
        if (t < 256) sscan[t] += v;
        __syncthreads();
    }
    if (t < 256) offl[t] = sscan[t] - curl[t];
    if (t == 0) offl[256] = sscan[255];
    for (int i = t; i < 256; i += 1024) curl[i] = 0;
    __syncthreads();
    for (int i = t; i < 4096; i += 1024) {
        int sn = newid[srcg[i] - nbase], dn = newid[dstg[i] - nbase];
        if (sn != 255 && dn != 255) {
            int slot = offl[dn] + atomicAdd(&curl[dn], 1);
            csr8[slot] = (unsigned char)sn;
        }
    }
    __syncthreads();

    // ================= phase-2: 2 GIN layers on 128 nodes =================
    unsigned short* aHi2 = (unsigned short*)(U + 65536);
    unsigned short* aLo2 = (unsigned short*)(U + 65536 + 32768);
    for (int L = 3; L < 5; ++L) {
        const float opEps = 1.f + epsArr[L];
        float agx[8], agy[8];
#pragma unroll
        for (int i = 0; i < 8; ++i) {
            int node = wv * 8 + i;
            int st = offl[node], en = offl[node + 1];
            float2 a = hF2[node * 64 + l];
            float ax = a.x * opEps, ay = a.y * opEps;
            int j = st;
            for (; j + 3 < en; j += 4) {
                int n0 = csr8[j], n1 = csr8[j + 1], n2 = csr8[j + 2], n3 = csr8[j + 3];
                float2 v0 = hF2[n0 * 64 + l];
                float2 v1 = hF2[n1 * 64 + l];
                float2 v2 = hF2[n2 * 64 + l];
                float2 v3 = hF2[n3 * 64 + l];
                ax += v0.x + v1.x + v2.x + v3.x;
                ay += v0.y + v1.y + v2.y + v3.y;
            }
            for (; j < en; ++j) {
                float2 v = hF2[csr8[j] * 64 + l];
                ax += v.x; ay += v.y;
            }
            agx[i] = ax; agy[i] = ay;
        }
        __syncthreads();
#pragma unroll
        for (int i = 0; i < 8; ++i) {
            int node = wv * 8 + i;
            int idx = (node * DD + l * 2) ^ ((node & 7) << 3);
            unsigned short hx = bf16_rne(agx[i]);
            unsigned short hy = bf16_rne(agy[i]);
            float rx = agx[i] - __uint_as_float((unsigned)hx << 16);
            float ry = agy[i] - __uint_as_float((unsigned)hy << 16);
            *(unsigned*)&aHi2[idx] = (unsigned)hx | ((unsigned)hy << 16);
            *(unsigned*)&aLo2[idx] = (unsigned)bf16_rne(rx) | ((unsigned)bf16_rne(ry) << 16);
        }
        const unsigned short* WH = wtHi + L * 16384;
        const unsigned short* WL = wtLo + L * 16384;
        f32x4 acc[8] = {};
        const int rowa = wv * 16 + la;  // valid for wv < 8
        const int aXor = (rowa & 7) << 3;
        for (int c = 0; c < 4; ++c) {
            __syncthreads();
            {
                int e0 = (t & 511) * 8;
                int n = e0 >> 5, kk = e0 & 31;
                int de = e0 ^ (((n >> 1) & 3) << 3);
                const bf16x8* gsrc = (const bf16x8*)((t < 512 ? WH : WL) + n * DD + c * 32 + kk);
                *(bf16x8*)&wS[t >> 9][de] = *gsrc;
            }
            __syncthreads();
            if (wv < 8) {
                int ai = (rowa * DD + c * 32 + kg * 8) ^ aXor;
                bf16x8 ah = *(const bf16x8*)&aHi2[ai];
                bf16x8 al = *(const bf16x8*)&aLo2[ai];
#pragma unroll
                for (int gi = 0; gi < 8; ++gi) {
                    int n = gi * 16 + la;
                    int bi = (n * 32 + kg * 8) ^ (((n >> 1) & 3) << 3);
                    bf16x8 bh = *(const bf16x8*)&wS[0][bi];
                    bf16x8 bl = *(const bf16x8*)&wS[1][bi];
                    acc[gi] = __builtin_amdgcn_mfma_f32_16x16x32_bf16(ah, bh, acc[gi], 0, 0, 0);
                    acc[gi] = __builtin_amdgcn_mfma_f32_16x16x32_bf16(ah, bl, acc[gi], 0, 0, 0);
                    acc[gi] = __builtin_amdgcn_mfma_f32_16x16x32_bf16(al, bh, acc[gi], 0, 0, 0);
                }
            }
        }
        __syncthreads();
        float* partS = (float*)(U + 65536);
        float* partQ = (float*)(U + 65536 + 4096);
        if (wv < 8) {
#pragma unroll
            for (int gi = 0; gi < 8; ++gi) {
                int col = gi * 16 + la;
                float bv = bg[L * DD + col];
                float s = 0.f, q = 0.f;
#pragma unroll
                for (int r = 0; r < 4; ++r) {
                    float o = acc[gi][r] + bv;
                    acc[gi][r] = o;
                    s += o; q += o * o;
                }
                s += __shfl_xor(s, 16); s += __shfl_xor(s, 32);
                q += __shfl_xor(q, 16); q += __shfl_xor(q, 32);
                if (kg == 0) { partS[wv * DD + col] = s; partQ[wv * DD + col] = q; }
            }
        }
        __syncthreads();
        if (t < DD) {
            float s = 0.f, q = 0.f;
#pragma unroll
            for (int i = 0; i < 8; ++i) { s += partS[i * DD + t]; q += partQ[i * DD + t]; }
            atomicAdd(&bnst[L * 256 + t], s);
            atomicAdd(&bnst[L * 256 + DD + t], q);
        }
        grid.sync();
        if (t < DD) {
            float s = __hip_atomic_load(&bnst[L * 256 + t], __ATOMIC_RELAXED, __HIP_MEMORY_SCOPE_AGENT);
            float q = __hip_atomic_load(&bnst[L * 256 + DD + t], __ATOMIC_RELAXED, __HIP_MEMORY_SCOPE_AGENT);
            float mu = s * INV_N2;
            float var = q * INV_N2 - mu * mu;
            float istd = rsqrtf(var + BN_EPS);
            float ga = gam[L * DD + t], be = bet[L * DD + t];
            scsh[t] = ga * istd;
            scsh[DD + t] = be - mu * ga * istd;
        }
        __syncthreads();
        if (wv < 8) {
#pragma unroll
            for (int gi = 0; gi < 8; ++gi) {
                int col = gi * 16 + la;
                float sc = scsh[col], sh = scsh[DD + col];
#pragma unroll
                for (int r = 0; r < 4; ++r) {
                    int row = wv * 16 + kg * 4 + r;
                    hF[row * DD + col] = fmaxf(acc[gi][r] * sc + sh, 0.f);
                }
            }
        }
        __syncthreads();
    }

    // ================= mean-pool + head + sigmoid =================
    {
        float* partP = (float*)(U + 65536);
        int c = t & 127, grp = t >> 7;  // 8 groups x 16 rows
        float s = 0.f;
        for (int r = grp * 16; r < grp * 16 + 16; ++r) s += hF[r * DD + c];
        partP[grp * DD + c] = s;
        float* oWl = (float*)(U + 65536 + 8192);
        for (int i = t; i < DD * OUTD; i += 1024) oWl[i] = oW[i];
        __syncthreads();
        if (t < DD) {
            float s2 = 0.f;
#pragma unroll
            for (int i = 0; i < 8; ++i) s2 += partP[i * DD + t];
            pooled[t] = s2 * (1.f / (float)KK);
        }
        __syncthreads();
        if (t < OUTD) {
            float o = ob[t];
            for (int k = 0; k < DD; ++k) o += pooled[k] * oWl[k * OUTD + t];
            out[g * OUTD + t] = 1.f / (1.f + expf(-o));
        }
    }
}

extern "C" void kernel_launch(void* const* d_in, const int* in_sizes, int n_in,
                              void* d_out, int out_size, void* d_ws, size_t ws_size,
                              hipStream_t stream) {
    const int*   x        = (const int*)d_in[0];
    const int*   ei       = (const int*)d_in[1];
    const float* atom_emb = (const float*)d_in[4];
    const float* convW    = (const float*)d_in[6];
    const float* convb    = (const float*)d_in[7];
    const float* gam      = (const float*)d_in[8];
    const float* bet      = (const float*)d_in[9];
    const float* eps      = (const float*)d_in[10];
    const float* tw       = (const float*)d_in[11];
    const float* oW       = (const float*)d_in[12];
    const float* ob       = (const float*)d_in[13];
    float* outp = (float*)d_out;

    char* p = (char*)d_ws;
    float* bnst = (float*)p;            p += (size_t)5 * 256 * 4;
    unsigned short* wtHi = (unsigned short*)p; p += (size_t)5 * DD * DD * 2;
    unsigned short* wtLo = (unsigned short*)p; p += (size_t)5 * DD * DD * 2;
    if ((size_t)(p - (char*)d_ws) > ws_size) return;

    hipMemsetAsync(bnst, 0, (size_t)5 * 256 * 4, stream);
    k_prepw<<<640, 128, 0, stream>>>(convW, wtHi, wtLo);

    void* args[] = {
        (void*)&x, (void*)&ei, (void*)&atom_emb, (void*)&wtHi, (void*)&wtLo,
        (void*)&convb, (void*)&gam, (void*)&bet, (void*)&eps, (void*)&tw,
        (void*)&oW, (void*)&ob, (void*)&bnst, (void*)&outp
    };
    hipLaunchCooperativeKernel((void*)k_mega, dim3(BB), dim3(1024), args, 0, stream);
}

// Round 6
// 361.800 us; speedup vs baseline: 2.2135x; 1.0009x over previous
//
#include <hip/hip_runtime.h>
#include <hip/hip_cooperative_groups.h>
#include <math.h>

namespace cg = cooperative_groups;

#define NN   65536
#define BB   256
#define NPGC 256
#define EE   1048576
#define DD   128
#define KK   128
#define NT2  32768
#define OUTD 12
#define BN_EPS 1e-5f
#define INV_N1 (1.f / 65536.f)
#define INV_N2 (1.f / 32768.f)

typedef __attribute__((ext_vector_type(8))) short bf16x8;
typedef __attribute__((ext_vector_type(4))) float f32x4;

__device__ __forceinline__ unsigned short bf16_rne(float v) {
    unsigned u = __float_as_uint(v);
    unsigned r = u + 0x7FFFu + ((u >> 16) & 1u);
    return (unsigned short)(r >> 16);
}

// ---------------- W prep: transpose + split f32 -> bf16 hi/lo, [layer][n][k] ----------------
__global__ void k_prepw(const float* __restrict__ Wg, unsigned short* __restrict__ wtHi,
                        unsigned short* __restrict__ wtLo) {
    int b = blockIdx.x;            // 0..639
    int l = b >> 7, n = b & 127;
    int k = threadIdx.x;           // 128
    float v = Wg[l * 16384 + k * 128 + n];
    unsigned short hb = bf16_rne(v);
    float hf = __uint_as_float((unsigned)hb << 16);
    unsigned short lb = bf16_rne(v - hf);
    wtHi[l * 16384 + n * 128 + k] = hb;
    wtLo[l * 16384 + n * 128 + k] = lb;
}

// ---------------- The whole network: one graph per block, h resident in LDS ----------------
// __launch_bounds__(1024, 4): 16 waves/block = 4 waves/SIMD (LDS caps at 1 block/CU anyway);
// min-waves-per-EU=4 lifts the VGPR cap to 128, eliminating the scratch spills seen at 64.
__global__ __launch_bounds__(1024, 4) void k_mega(
    const int* __restrict__ x, const int* __restrict__ ei,
    const float* __restrict__ emb,
    const unsigned short* __restrict__ wtHi, const unsigned short* __restrict__ wtLo,
    const float* __restrict__ bg, const float* __restrict__ gam,
    const float* __restrict__ bet, const float* __restrict__ epsArr,
    const float* __restrict__ tw, const float* __restrict__ oW,
    const float* __restrict__ ob, float* __restrict__ bnst,
    float* __restrict__ out)
{
    cg::grid_group grid = cg::this_grid();

    __shared__ __align__(16) unsigned char U[131072];      // h f32 (256x128) OR aHi/aLo bf16
    __shared__ __align__(16) unsigned short wS[2][4096];   // W chunk hi/lo (16KB); aliased by xr early
    __shared__ unsigned char csr8[4096];
    __shared__ int offl[257];
    __shared__ int curl[256];
    __shared__ int sscan[256];
    __shared__ float score[256];
    __shared__ float scsh[256];    // sc[0..127], sh[128..255]
    __shared__ float wlds[128];
    __shared__ float pooled[128];
    __shared__ unsigned char newid[256];
    __shared__ unsigned char perml[128];
    __shared__ unsigned char flg[256];
    __shared__ float invn_s;

    float* hF = (float*)U;
    float2* hF2 = (float2*)U;
    unsigned short* aHi = (unsigned short*)U;
    unsigned short* aLo = (unsigned short*)(U + 65536);

    const int g = blockIdx.x;
    const int t = threadIdx.x;
    const int wv = t >> 6, l = t & 63;
    const int la = l & 15, kg = l >> 4;
    const int nbase = g * NPGC;
    const int* srcg = ei + g * 4096;
    const int* dstg = ei + EE + g * 4096;

    // ================= atom encoder =================
    {
        int* xr = (int*)wS;  // 2304 ints, fits in 16KB
        for (int i = t; i < NPGC * 9; i += 1024) xr[i] = x[nbase * 9 + i];
        __syncthreads();
        int n = t >> 2, cq = (t & 3) << 5;
        f32x4 a8[8] = {};
#pragma unroll
        for (int f = 0; f < 9; ++f) {
            const f32x4* ep = (const f32x4*)&emb[(size_t)((f << 7) + xr[n * 9 + f]) * DD + cq];
#pragma unroll
            for (int q = 0; q < 8; ++q) a8[q] += ep[q];
        }
        f32x4* hq = (f32x4*)&hF[n * DD + cq];
#pragma unroll
        for (int q = 0; q < 8; ++q) hq[q] = a8[q];
    }

    // ================= CSR1 (block-local) =================
    for (int i = t; i < 256; i += 1024) curl[i] = 0;
    __syncthreads();
    for (int i = t; i < 4096; i += 1024) atomicAdd(&curl[dstg[i] - nbase], 1);
    __syncthreads();
    if (t < 256) sscan[t] = curl[t];
    __syncthreads();
    for (int d = 1; d < 256; d <<= 1) {
        int v = (t < 256 && t >= d) ? sscan[t - d] : 0;
        __syncthreads();
        if (t < 256) sscan[t] += v;
        __syncthreads();
    }
    if (t < 256) offl[t] = sscan[t] - curl[t];
    if (t == 0) offl[256] = 4096;
    for (int i = t; i < 256; i += 1024) curl[i] = 0;
    __syncthreads();
    for (int i = t; i < 4096; i += 1024) {
        int d = dstg[i] - nbase;
        int slot = offl[d] + atomicAdd(&curl[d], 1);
        csr8[slot] = (unsigned char)(srcg[i] - nbase);
    }
    __syncthreads();

    // ================= phase-1: 3 GIN layers on 256 nodes =================
    for (int L = 0; L < 3; ++L) {
        const float opEps = 1.f + epsArr[L];
        // ---- aggregate into registers (wave wv owns nodes wv*16..+15; lane = 2 channels) ----
        float agx[16], agy[16];
#pragma unroll
        for (int i = 0; i < 16; ++i) {
            int node = wv * 16 + i;
            int st = offl[node], en = offl[node + 1];
            float2 a = hF2[node * 64 + l];
            float ax = a.x * opEps, ay = a.y * opEps;
            int j = st;
            for (; j + 3 < en; j += 4) {
                int n0 = csr8[j], n1 = csr8[j + 1], n2 = csr8[j + 2], n3 = csr8[j + 3];
                float2 v0 = hF2[n0 * 64 + l];
                float2 v1 = hF2[n1 * 64 + l];
                float2 v2 = hF2[n2 * 64 + l];
                float2 v3 = hF2[n3 * 64 + l];
                ax += v0.x + v1.x + v2.x + v3.x;
                ay += v0.y + v1.y + v2.y + v3.y;
            }
            for (; j < en; ++j) {
                float2 v = hF2[csr8[j] * 64 + l];
                ax += v.x; ay += v.y;
            }
            agx[i] = ax; agy[i] = ay;
        }
        __syncthreads();
        // ---- overwrite union with swizzled bf16 hi/lo A tiles ----
#pragma unroll
        for (int i = 0; i < 16; ++i) {
            int node = wv * 16 + i;
            int idx = (node * DD + l * 2) ^ ((node & 7) << 3);
            unsigned short hx = bf16_rne(agx[i]);
            unsigned short hy = bf16_rne(agy[i]);
            float rx = agx[i] - __uint_as_float((unsigned)hx << 16);
            float ry = agy[i] - __uint_as_float((unsigned)hy << 16);
            *(unsigned*)&aHi[idx] = (unsigned)hx | ((unsigned)hy << 16);
            *(unsigned*)&aLo[idx] = (unsigned)bf16_rne(rx) | ((unsigned)bf16_rne(ry) << 16);
        }
        // ---- MFMA: 16 waves x 16-row stripes, 8 col groups, split-bf16 3 products ----
        const unsigned short* WH = wtHi + L * 16384;
        const unsigned short* WL = wtLo + L * 16384;
        f32x4 acc[8] = {};
        const int rowa = wv * 16 + la;
        const int aXor = (rowa & 7) << 3;
        for (int c = 0; c < 4; ++c) {
            __syncthreads();
            {
                int e0 = (t & 511) * 8;
                int n = e0 >> 5, kk = e0 & 31;
                int de = e0 ^ (((n >> 1) & 3) << 3);
                const bf16x8* gsrc = (const bf16x8*)((t < 512 ? WH : WL) + n * DD + c * 32 + kk);
                *(bf16x8*)&wS[t >> 9][de] = *gsrc;
            }
            __syncthreads();
            int ai = (rowa * DD + c * 32 + kg * 8) ^ aXor;
            bf16x8 ah = *(const bf16x8*)&aHi[ai];
            bf16x8 al = *(const bf16x8*)&aLo[ai];
#pragma unroll
            for (int gi = 0; gi < 8; ++gi) {
                int n = gi * 16 + la;
                int bi = (n * 32 + kg * 8) ^ (((n >> 1) & 3) << 3);
                bf16x8 bh = *(const bf16x8*)&wS[0][bi];
                bf16x8 bl = *(const bf16x8*)&wS[1][bi];
                acc[gi] = __builtin_amdgcn_mfma_f32_16x16x32_bf16(ah, bh, acc[gi], 0, 0, 0);
                acc[gi] = __builtin_amdgcn_mfma_f32_16x16x32_bf16(ah, bl, acc[gi], 0, 0, 0);
                acc[gi] = __builtin_amdgcn_mfma_f32_16x16x32_bf16(al, bh, acc[gi], 0, 0, 0);
            }
        }
        __syncthreads();
        // ---- bias + block-partial BN stats (union reused as scratch) ----
        float* partS = (float*)U;
        float* partQ = (float*)(U + 8192);
#pragma unroll
        for (int gi = 0; gi < 8; ++gi) {
            int col = gi * 16 + la;
            float bv = bg[L * DD + col];
            float s = 0.f, q = 0.f;
#pragma unroll
            for (int r = 0; r < 4; ++r) {
                float o = acc[gi][r] + bv;
                acc[gi][r] = o;
                s += o; q += o * o;
            }
            s += __shfl_xor(s, 16); s += __shfl_xor(s, 32);
            q += __shfl_xor(q, 16); q += __shfl_xor(q, 32);
            if (kg == 0) { partS[wv * DD + col] = s; partQ[wv * DD + col] = q; }
        }
        __syncthreads();
        if (t < DD) {
            float s = 0.f, q = 0.f;
#pragma unroll
            for (int i = 0; i < 16; ++i) { s += partS[i * DD + t]; q += partQ[i * DD + t]; }
            atomicAdd(&bnst[L * 256 + t], s);
            atomicAdd(&bnst[L * 256 + DD + t], q);
        }
        grid.sync();
        if (t < DD) {
            float s = __hip_atomic_load(&bnst[L * 256 + t], __ATOMIC_RELAXED, __HIP_MEMORY_SCOPE_AGENT);
            float q = __hip_atomic_load(&bnst[L * 256 + DD + t], __ATOMIC_RELAXED, __HIP_MEMORY_SCOPE_AGENT);
            float mu = s * INV_N1;
            float var = q * INV_N1 - mu * mu;
            float istd = rsqrtf(var + BN_EPS);
            float ga = gam[L * DD + t], be = bet[L * DD + t];
            scsh[t] = ga * istd;
            scsh[DD + t] = be - mu * ga * istd;
        }
        __syncthreads();
        // ---- BN apply + ReLU -> h f32 back into union ----
#pragma unroll
        for (int gi = 0; gi < 8; ++gi) {
            int col = gi * 16 + la;
            float sc = scsh[col], sh = scsh[DD + col];
#pragma unroll
            for (int r = 0; r < 4; ++r) {
                int row = wv * 16 + kg * 4 + r;
                hF[row * DD + col] = fmaxf(acc[gi][r] * sc + sh, 0.f);
            }
        }
        __syncthreads();
    }

    // ================= score / top-k / gate (block-local) =================
    if (t < DD) wlds[t] = tw[t];
    __syncthreads();
    if (t < DD) score[t] = wlds[t] * wlds[t];
    __syncthreads();
    for (int d = 64; d > 0; d >>= 1) {
        if (t < d) score[t] += score[t + d];
        __syncthreads();
    }
    if (t == 0) invn_s = rsqrtf(score[0]);
    __syncthreads();
    {
        float wx = wlds[l * 2], wy = wlds[l * 2 + 1];
        for (int i = 0; i < 16; ++i) {
            int node = wv * 16 + i;
            float2 a = hF2[node * 64 + l];
            float p = a.x * wx + a.y * wy;
            p += __shfl_xor(p, 32); p += __shfl_xor(p, 16); p += __shfl_xor(p, 8);
            p += __shfl_xor(p, 4);  p += __shfl_xor(p, 2);  p += __shfl_xor(p, 1);
            if (l == 0) score[node] = p * invn_s;
        }
    }
    __syncthreads();
    if (t < 256) {
        float v = score[t];
        int rank = 0;
        for (int j = 0; j < 256; ++j) {
            float u = score[j];
            rank += (u > v) || (u == v && j < t);
        }
        int sel = rank < KK ? 1 : 0;
        flg[t] = (unsigned char)sel;
        sscan[t] = sel;
    }
    __syncthreads();
    for (int d = 1; d < 256; d <<= 1) {
        int v = (t < 256 && t >= d) ? sscan[t - d] : 0;
        __syncthreads();
        if (t < 256) sscan[t] += v;
        __syncthreads();
    }
    if (t < 256) {
        if (flg[t]) {
            int m = sscan[t] - 1;
            newid[t] = (unsigned char)m;
            perml[m] = (unsigned char)t;
        } else {
            newid[t] = 0xFF;
        }
    }
    __syncthreads();
    // gate: 8 threads per kept row, 16 channels each; regs carry across the overwrite
    {
        int m = t >> 3, cs = (t & 7) << 4;
        int src = perml[m];
        float tg = tanhf(score[src]);
        f32x4 gv[4];
#pragma unroll
        for (int q = 0; q < 4; ++q) {
            gv[q] = ((const f32x4*)&hF[src * DD + cs])[q];
            gv[q].x *= tg; gv[q].y *= tg; gv[q].z *= tg; gv[q].w *= tg;
        }
        __syncthreads();
#pragma unroll
        for (int q = 0; q < 4; ++q) ((f32x4*)&hF[m * DD + cs])[q] = gv[q];
    }
    __syncthreads();

    // ================= CSR2 (kept edges, block-local) =================
    for (int i = t; i < 256; i += 1024) curl[i] = 0;
    __syncthreads();
    for (int i = t; i < 4096; i += 1024) {
        int sn = newid[srcg[i] - nbase], dn = newid[dstg[i] - nbase];
        if (sn != 255 && dn != 255) atomicAdd(&curl[dn], 1);
    }
    __syncthreads();
    if (t < 256) sscan[t] = curl[t];
    __syncthreads();
    for (int d = 1; d < 256; d <<= 1) {
        int v = (t < 256 && t >= d) ? sscan[t - d] : 0;
        __syncthreads();
        if (t < 256) sscan[t] += v;
        __syncthreads();
    }
    if (t < 256) offl[t] = sscan[t] - curl[t];
    if (t == 0) offl[256] = sscan[255];
    for (int i = t; i < 256; i += 1024) curl[i] = 0;
    __syncthreads();
    for (int i = t; i < 4096; i += 1024) {
        int sn = newid[srcg[i] - nbase], dn = newid[dstg[i] - nbase];
        if (sn != 255 && dn != 255) {
            int slot = offl[dn] + atomicAdd(&curl[dn], 1);
            csr8[slot] = (unsigned char)sn;
        }
    }
    __syncthreads();

    // ================= phase-2: 2 GIN layers on 128 nodes =================
    unsigned short* aHi2 = (unsigned short*)(U + 65536);
    unsigned short* aLo2 = (unsigned short*)(U + 65536 + 32768);
    for (int L = 3; L < 5; ++L) {
        const float opEps = 1.f + epsArr[L];
        float agx[8], agy[8];
#pragma unroll
        for (int i = 0; i < 8; ++i) {
            int node = wv * 8 + i;
            int st = offl[node], en = offl[node + 1];
            float2 a = hF2[node * 64 + l];
            float ax = a.x * opEps, ay = a.y * opEps;
            int j = st;
            for (; j + 3 < en; j += 4) {
                int n0 = csr8[j], n1 = csr8[j + 1], n2 = csr8[j + 2], n3 = csr8[j + 3];
                float2 v0 = hF2[n0 * 64 + l];
                float2 v1 = hF2[n1 * 64 + l];
                float2 v2 = hF2[n2 * 64 + l];
                float2 v3 = hF2[n3 * 64 + l];
                ax += v0.x + v1.x + v2.x + v3.x;
                ay += v0.y + v1.y + v2.y + v3.y;
            }
            for (; j < en; ++j) {
                float2 v = hF2[csr8[j] * 64 + l];
                ax += v.x; ay += v.y;
            }
            agx[i] = ax; agy[i] = ay;
        }
        __syncthreads();
#pragma unroll
        for (int i = 0; i < 8; ++i) {
            int node = wv * 8 + i;
            int idx = (node * DD + l * 2) ^ ((node & 7) << 3);
            unsigned short hx = bf16_rne(agx[i]);
            unsigned short hy = bf16_rne(agy[i]);
            float rx = agx[i] - __uint_as_float((unsigned)hx << 16);
            float ry = agy[i] - __uint_as_float((unsigned)hy << 16);
            *(unsigned*)&aHi2[idx] = (unsigned)hx | ((unsigned)hy << 16);
            *(unsigned*)&aLo2[idx] = (unsigned)bf16_rne(rx) | ((unsigned)bf16_rne(ry) << 16);
        }
        const unsigned short* WH = wtHi + L * 16384;
        const unsigned short* WL = wtLo + L * 16384;
        f32x4 acc[8] = {};
        const int rowa = wv * 16 + la;  // valid for wv < 8
        const int aXor = (rowa & 7) << 3;
        for (int c = 0; c < 4; ++c) {
            __syncthreads();
            {
                int e0 = (t & 511) * 8;
                int n = e0 >> 5, kk = e0 & 31;
                int de = e0 ^ (((n >> 1) & 3) << 3);
                const bf16x8* gsrc = (const bf16x8*)((t < 512 ? WH : WL) + n * DD + c * 32 + kk);
                *(bf16x8*)&wS[t >> 9][de] = *gsrc;
            }
            __syncthreads();
            if (wv < 8) {
                int ai = (rowa * DD + c * 32 + kg * 8) ^ aXor;
                bf16x8 ah = *(const bf16x8*)&aHi2[ai];
                bf16x8 al = *(const bf16x8*)&aLo2[ai];
#pragma unroll
                for (int gi = 0; gi < 8; ++gi) {
                    int n = gi * 16 + la;
                    int bi = (n * 32 + kg * 8) ^ (((n >> 1) & 3) << 3);
                    bf16x8 bh = *(const bf16x8*)&wS[0][bi];
                    bf16x8 bl = *(const bf16x8*)&wS[1][bi];
                    acc[gi] = __builtin_amdgcn_mfma_f32_16x16x32_bf16(ah, bh, acc[gi], 0, 0, 0);
                    acc[gi] = __builtin_amdgcn_mfma_f32_16x16x32_bf16(ah, bl, acc[gi], 0, 0, 0);
                    acc[gi] = __builtin_amdgcn_mfma_f32_16x16x32_bf16(al, bh, acc[gi], 0, 0, 0);
                }
            }
        }
        __syncthreads();
        float* partS = (float*)(U + 65536);
        float* partQ = (float*)(U + 65536 + 4096);
        if (wv < 8) {
#pragma unroll
            for (int gi = 0; gi < 8; ++gi) {
                int col = gi * 16 + la;
                float bv = bg[L * DD + col];
                float s = 0.f, q = 0.f;
#pragma unroll
                for (int r = 0; r < 4; ++r) {
                    float o = acc[gi][r] + bv;
                    acc[gi][r] = o;
                    s += o; q += o * o;
                }
                s += __shfl_xor(s, 16); s += __shfl_xor(s, 32);
                q += __shfl_xor(q, 16); q += __shfl_xor(q, 32);
                if (kg == 0) { partS[wv * DD + col] = s; partQ[wv * DD + col] = q; }
            }
        }
        __syncthreads();
        if (t < DD) {
            float s = 0.f, q = 0.f;
#pragma unroll
            for (int i = 0; i < 8; ++i) { s += partS[i * DD + t]; q += partQ[i * DD + t]; }
            atomicAdd(&bnst[L * 256 + t], s);
            atomicAdd(&bnst[L * 256 + DD + t], q);
        }
        grid.sync();
        if (t < DD) {
            float s = __hip_atomic_load(&bnst[L * 256 + t], __ATOMIC_RELAXED, __HIP_MEMORY_SCOPE_AGENT);
            float q = __hip_atomic_load(&bnst[L * 256 + DD + t], __ATOMIC_RELAXED, __HIP_MEMORY_SCOPE_AGENT);
            float mu = s * INV_N2;
            float var = q * INV_N2 - mu * mu;
            float istd = rsqrtf(var + BN_EPS);
            float ga = gam[L * DD + t], be = bet[L * DD + t];
            scsh[t] = ga * istd;
            scsh[DD + t] = be - mu * ga * istd;
        }
        __syncthreads();
        if (wv < 8) {
#pragma unroll
            for (int gi = 0; gi < 8; ++gi) {
                int col = gi * 16 + la;
                float sc = scsh[col], sh = scsh[DD + col];
#pragma unroll
                for (int r = 0; r < 4; ++r) {
                    int row = wv * 16 + kg * 4 + r;
                    hF[row * DD + col] = fmaxf(acc[gi][r] * sc + sh, 0.f);
                }
            }
        }
        __syncthreads();
    }

    // ================= mean-pool + head + sigmoid =================
    {
        float* partP = (float*)(U + 65536);
        int c = t & 127, grp = t >> 7;  // 8 groups x 16 rows
        float s = 0.f;
        for (int r = grp * 16; r < grp * 16 + 16; ++r) s += hF[r * DD + c];
        partP[grp * DD + c] = s;
        float* oWl = (float*)(U + 65536 + 8192);
        for (int i = t; i < DD * OUTD; i += 1024) oWl[i] = oW[i];
        __syncthreads();
        if (t < DD) {
            float s2 = 0.f;
#pragma unroll
            for (int i = 0; i < 8; ++i) s2 += partP[i * DD + t];
            pooled[t] = s2 * (1.f / (float)KK);
        }
        __syncthreads();
        if (t < OUTD) {
            float o = ob[t];
            for (int k = 0; k < DD; ++k) o += pooled[k] * oWl[k * OUTD + t];
            out[g * OUTD + t] = 1.f / (1.f + expf(-o));
        }
    }
}

extern "C" void kernel_launch(void* const* d_in, const int* in_sizes, int n_in,
                              void* d_out, int out_size, void* d_ws, size_t ws_size,
                              hipStream_t stream) {
    const int*   x        = (const int*)d_in[0];
    const int*   ei       = (const int*)d_in[1];
    const float* atom_emb = (const float*)d_in[4];
    const float* convW    = (const float*)d_in[6];
    const float* convb    = (const float*)d_in[7];
    const float* gam      = (const float*)d_in[8];
    const float* bet      = (const float*)d_in[9];
    const float* eps      = (const float*)d_in[10];
    const float* tw       = (const float*)d_in[11];
    const float* oW       = (const float*)d_in[12];
    const float* ob       = (const float*)d_in[13];
    float* outp = (float*)d_out;

    char* p = (char*)d_ws;
    float* bnst = (float*)p;            p += (size_t)5 * 256 * 4;
    unsigned short* wtHi = (unsigned short*)p; p += (size_t)5 * DD * DD * 2;
    unsigned short* wtLo = (unsigned short*)p; p += (size_t)5 * DD * DD * 2;
    if ((size_t)(p - (char*)d_ws) > ws_size) return;

    hipMemsetAsync(bnst, 0, (size_t)5 * 256 * 4, stream);
    k_prepw<<<640, 128, 0, stream>>>(convW, wtHi, wtLo);

    void* args[] = {
        (void*)&x, (void*)&ei, (void*)&atom_emb, (void*)&wtHi, (void*)&wtLo,
        (void*)&convb, (void*)&gam, (void*)&bet, (void*)&eps, (void*)&tw,
        (void*)&oW, (void*)&ob, (void*)&bnst, (void*)&outp
    };
    hipLaunchCooperativeKernel((void*)k_mega, dim3(BB), dim3(1024), args, 0, stream);
}